// Round 23
// baseline (1979.384 us; speedup 1.0000x reference)
//
#include <hip/hip_runtime.h>

#define DEV __device__ __forceinline__

typedef unsigned short u16;
typedef unsigned int u32;
typedef __attribute__((ext_vector_type(8))) _Float16 h8_t;  // 8 f16 (4 VGPR)
typedef __attribute__((ext_vector_type(4))) float f4_t;

constexpr int T_SEQ = 1024;
constexpr int DMODEL = 512;
constexpr int NPAT = 512;

// ---------------- epilogue modes ----------------
enum {
  E_BIAS = 0,
  E_VQ = 5,
  E_RES = 6,
  E_POS = 8,
  E_GUM2 = 9,
  E_GELU2 = 10,
  E_QKV2 = 11
};

// ---------------- fp16 double-split helpers (err ~2^-22, fp32-grade) ---------
DEV float h2f(u16 h) { return (float)__builtin_bit_cast(_Float16, h); }
DEV void split2(float x, u16& h, u16& l) {
  _Float16 hh = (_Float16)x;
  float r = x - (float)hh;
  _Float16 ll = (_Float16)r;
  h = __builtin_bit_cast(u16, hh);
  l = __builtin_bit_cast(u16, ll);
}

DEV f4_t mfh(h8_t a, h8_t b, f4_t c) {
  return __builtin_amdgcn_mfma_f32_16x16x32_f16(a, b, c, 0, 0, 0);
}
// 3-product double-split accumulate: AB = AhBh + AhBl + AlBh (+O(2^-22))
DEV f4_t prod3(h8_t ah, h8_t al, h8_t bh, h8_t bl, f4_t c) {
  c = mfh(ah, bh, c);
  c = mfh(ah, bl, c);
  c = mfh(al, bh, c);
  return c;
}

// async global->LDS, 16B per lane; LDS dest = base + lane*16 (wave-uniform base)
typedef const __attribute__((address_space(1))) unsigned char* gas_t;
typedef __attribute__((address_space(3))) unsigned char* las_t;
DEV void gload16(const u16* g, u16* l) {
  __builtin_amdgcn_global_load_lds((gas_t)(const void*)g, (las_t)(void*)l, 16,
                                   0, 0);
}

// shared epilogue applier (C frag: col = lane&15, row = 4*(lane>>4)+i)
template <int EPI>
DEV void apply_epi(float v, int m, int c, int N, const float* bias_v,
                   const float* res, float* Cf, u16* Ch, u16* Cl, float invt) {
  const size_t idx = (size_t)m * N + c;
  if constexpr (EPI == E_BIAS) {
    Cf[idx] = v + bias_v[0];
  } else if constexpr (EPI == E_VQ) {
    Cf[idx] = v * invt;
  } else if constexpr (EPI == E_RES) {
    Cf[idx] = v + bias_v[0] + res[idx];
  } else if constexpr (EPI == E_POS) {
    Cf[idx] = v + res[(size_t)(m & 1023) * N + c];
  } else if constexpr (EPI == E_GUM2) {
    float t = 4.0f * v + 2.0f * res[idx];
    u16 h2, l2;
    split2(t, h2, l2);
    Ch[idx] = h2;
    Cl[idx] = l2;
  } else if constexpr (EPI == E_GELU2) {
    float t = v + bias_v[0];
    float g = 0.5f * t * (1.0f + erff(t * 0.7071067811865476f));
    u16 h2, l2;
    split2(g, h2, l2);
    Ch[idx] = h2;
    Cl[idx] = l2;
  } else if constexpr (EPI == E_QKV2) {
    float t = v + bias_v[0];
    u16 h2, l2;
    split2(t, h2, l2);
    size_t o;
    if (c < 512) {
      o = (size_t)m * 512 + c;                    // Q [B,T,512]
    } else if (c < 1024) {
      o = 4194304 + (size_t)m * 512 + (c - 512);  // K [B,T,512]
    } else {
      int cc = c - 1024, hh2 = cc >> 6, dd = cc & 63;
      int bb2 = m >> 10, tt2 = m & 1023;
      o = 8388608 + (((size_t)(bb2 * 8 + hh2) * 64 + dd) << 10) + tt2;  // Vt
    }
    Ch[o] = h2;
    Cl[o] = l2;
  }
}

// ---------------- MFMA GEMM, fp16 double-split (fp32-accurate) ---------------
// 4-wave BM=64 x BN=128. R23: A-fragments loaded DIRECTLY from global into
// registers (wave-private rows; L1/L2 serves the 2x wy-sharing), register
// double-buffered one K-step ahead via 2x-unrolled loop (static indices).
// LDS stages only B: 32KB dbuf -> 4 blk/CU = 16 waves/CU (was 3 blk/12 waves).
// Barrier now guards only 4 B-chunks/thread. Math order identical to champion.
template <int BM, int EPI>
__global__ __launch_bounds__(256, BM == 64 ? 4 : 2) void gemm_mf(
    const u16* __restrict__ Ah, const u16* __restrict__ Al,
    const u16* __restrict__ Bh, const u16* __restrict__ Bl,
    const float* __restrict__ bias, const float* __restrict__ res,
    float* __restrict__ Cf, u16* __restrict__ Ch, u16* __restrict__ Cl, int N,
    int KK, int lda, int ldb, int gx, const int* __restrict__ ep,
    const int* __restrict__ tot) {
  constexpr int MT = BM / 32;
  __shared__ __align__(16) u16 BsH[2][128][4][8], BsL[2][128][4][8];
  const int tid = threadIdx.x;
  const int w = tid >> 6, lane = tid & 63;
  const int wy = w >> 1, wx = w & 1;
  const int lr = lane & 15, lg = lane >> 4;

  const int nwg = gridDim.x;
  const int bid = blockIdx.x;
  const int qq = nwg >> 3;
  const int wg = (bid & 7) * qq + (bid >> 3);
  const int by = wg / gx, bx = wg % gx;
  const int bm = by * BM, bn = bx * 128;

  const int rowl = lane >> 2, slot4 = lane & 3;

  auto STAGE = [&](int k0, int buf) {
#pragma unroll
    for (int it = 0; it < 4; ++it) {  // B: 16 chunks (2 planes x 8)
      const int f = w + 4 * it;
      const int plane = f >> 3;
      const int ch = f & 7;
      const int row = ch * 16 + rowl;
      const int kp = slot4 ^ ((row >> 1) & 3);
      const size_t g = (size_t)(bn + row) * ldb + k0 + kp * 8;
      if (plane == 0)
        gload16(&Bh[g], &BsH[buf][0][0][0] + ch * 512);
      else
        gload16(&Bl[g], &BsL[buf][0][0][0] + ch * 512);
    }
  };

  auto LOAD_A = [&](int k0, h8_t(&ah)[MT], h8_t(&al)[MT]) {
#pragma unroll
    for (int mt = 0; mt < MT; ++mt) {
      const size_t g =
          (size_t)(bm + wy * (BM / 2) + mt * 16 + lr) * lda + k0 + lg * 8;
      ah[mt] = *(const h8_t*)&Ah[g];
      al[mt] = *(const h8_t*)&Al[g];
    }
  };

  f4_t acc[MT][4];
#pragma unroll
  for (int mt = 0; mt < MT; ++mt)
#pragma unroll
    for (int nt = 0; nt < 4; ++nt) acc[mt][nt] = (f4_t){0.f, 0.f, 0.f, 0.f};

  auto KSTEP = [&](int buf, h8_t(&ah)[MT], h8_t(&al)[MT]) {
    h8_t fbh[4], fbl[4];
#pragma unroll
    for (int nt = 0; nt < 4; ++nt) {
      int col = wx * 64 + nt * 16 + lr;
      int slot = lg ^ ((col >> 1) & 3);
      fbh[nt] = *(const h8_t*)&BsH[buf][col][slot][0];
      fbl[nt] = *(const h8_t*)&BsL[buf][col][slot][0];
    }
#pragma unroll
    for (int mt = 0; mt < MT; ++mt)
#pragma unroll
      for (int nt = 0; nt < 4; ++nt)
        acc[mt][nt] = prod3(ah[mt], al[mt], fbh[nt], fbl[nt], acc[mt][nt]);
  };

  // nsteps even for all uses (K in {512,1024,2048})
  const int nsteps = KK / 32;
  h8_t a0h[MT], a0l[MT], a1h[MT], a1l[MT];
  STAGE(0, 0);
  LOAD_A(0, a0h, a0l);
  __syncthreads();
  for (int s = 0; s < nsteps; s += 2) {
    // even step: read buf0 + a0; prefetch tile s+1 (buf1, a1)
    STAGE((s + 1) * 32, 1);
    LOAD_A((s + 1) * 32, a1h, a1l);
    KSTEP(0, a0h, a0l);
    __syncthreads();
    // odd step: read buf1 + a1; prefetch tile s+2 (buf0, a0)
    if (s + 2 < nsteps) {
      STAGE((s + 2) * 32, 0);
      LOAD_A((s + 2) * 32, a0h, a0l);
    }
    KSTEP(1, a1h, a1l);
    __syncthreads();
  }

  float bv[4];
  if constexpr (EPI == E_BIAS || EPI == E_RES || EPI == E_GELU2 ||
                EPI == E_QKV2) {
#pragma unroll
    for (int nt = 0; nt < 4; ++nt) bv[nt] = bias[bn + wx * 64 + nt * 16 + lr];
  }
  float invt = 1.0f;
  if constexpr (EPI == E_VQ) {
    float tt = 1.0f - 0.5f * (float)ep[0] / (float)tot[0];
    invt = 1.0f / fmaxf(0.5f, tt);
  }
#pragma unroll
  for (int mt = 0; mt < MT; ++mt)
#pragma unroll
    for (int nt = 0; nt < 4; ++nt) {
      const int c = bn + wx * 64 + nt * 16 + lr;
#pragma unroll
      for (int i = 0; i < 4; ++i) {
        const int m = bm + wy * (BM / 2) + mt * 16 + 4 * lg + i;
        apply_epi<EPI>(acc[mt][nt][i], m, c, N, &bv[nt], res, Cf, Ch, Cl,
                       invt);
      }
    }
}

// ---------------- 8-wave MFMA GEMM: BM=64 x BN=256, 512 threads --------------
// R23: same A-direct mechanism. LDS B-only 64KB dbuf -> 2 blk/CU; stage
// chunks 5->4/thread, ds_reads 12->8/wave-step. N>=1024 GEMMs.
template <int EPI>
__global__ __launch_bounds__(512, 2) void gemm_mf8(
    const u16* __restrict__ Ah, const u16* __restrict__ Al,
    const u16* __restrict__ Bh, const u16* __restrict__ Bl,
    const float* __restrict__ bias, const float* __restrict__ res,
    float* __restrict__ Cf, u16* __restrict__ Ch, u16* __restrict__ Cl, int N,
    int KK, int lda, int ldb, int gx) {
  __shared__ __align__(16) u16 BsH[2][256][4][8], BsL[2][256][4][8];
  const int tid = threadIdx.x;
  const int w = tid >> 6, lane = tid & 63;
  const int wy = w >> 2, wx = w & 3;  // 2x4 wave grid
  const int lr = lane & 15, lg = lane >> 4;

  const int nwg = gridDim.x;
  const int bid = blockIdx.x;
  const int qq = nwg >> 3;
  const int wg = (bid & 7) * qq + (bid >> 3);
  const int by = wg / gx, bx = wg % gx;
  const int bm = by * 64, bn = bx * 256;

  const int rowl = lane >> 2, slot4 = lane & 3;

  auto STAGE = [&](int k0, int buf) {
#pragma unroll
    for (int it = 0; it < 4; ++it) {  // B: 32 chunks (2 planes x 16)
      const int f = w + 8 * it;       // 0..31
      const int plane = f >> 4, ch = f & 15;
      const int row = ch * 16 + rowl;
      const int kp = slot4 ^ ((row >> 1) & 3);
      const size_t g = (size_t)(bn + row) * ldb + k0 + kp * 8;
      if (plane == 0)
        gload16(&Bh[g], &BsH[buf][0][0][0] + ch * 512);
      else
        gload16(&Bl[g], &BsL[buf][0][0][0] + ch * 512);
    }
  };

  auto LOAD_A = [&](int k0, h8_t(&ah)[2], h8_t(&al)[2]) {
#pragma unroll
    for (int mt = 0; mt < 2; ++mt) {
      const size_t g =
          (size_t)(bm + wy * 32 + mt * 16 + lr) * lda + k0 + lg * 8;
      ah[mt] = *(const h8_t*)&Ah[g];
      al[mt] = *(const h8_t*)&Al[g];
    }
  };

  f4_t acc[2][4];
#pragma unroll
  for (int mt = 0; mt < 2; ++mt)
#pragma unroll
    for (int nt = 0; nt < 4; ++nt) acc[mt][nt] = (f4_t){0.f, 0.f, 0.f, 0.f};

  auto KSTEP = [&](int buf, h8_t(&ah)[2], h8_t(&al)[2]) {
    h8_t fbh[4], fbl[4];
#pragma unroll
    for (int nt = 0; nt < 4; ++nt) {
      int col = wx * 64 + nt * 16 + lr;
      int slot = lg ^ ((col >> 1) & 3);
      fbh[nt] = *(const h8_t*)&BsH[buf][col][slot][0];
      fbl[nt] = *(const h8_t*)&BsL[buf][col][slot][0];
    }
#pragma unroll
    for (int mt = 0; mt < 2; ++mt)
#pragma unroll
      for (int nt = 0; nt < 4; ++nt)
        acc[mt][nt] = prod3(ah[mt], al[mt], fbh[nt], fbl[nt], acc[mt][nt]);
  };

  const int nsteps = KK / 32;  // even
  h8_t a0h[2], a0l[2], a1h[2], a1l[2];
  STAGE(0, 0);
  LOAD_A(0, a0h, a0l);
  __syncthreads();
  for (int s = 0; s < nsteps; s += 2) {
    STAGE((s + 1) * 32, 1);
    LOAD_A((s + 1) * 32, a1h, a1l);
    KSTEP(0, a0h, a0l);
    __syncthreads();
    if (s + 2 < nsteps) {
      STAGE((s + 2) * 32, 0);
      LOAD_A((s + 2) * 32, a0h, a0l);
    }
    KSTEP(1, a1h, a1l);
    __syncthreads();
  }

  float bv[4];
  if constexpr (EPI == E_BIAS || EPI == E_RES || EPI == E_GELU2 ||
                EPI == E_QKV2) {
#pragma unroll
    for (int nt = 0; nt < 4; ++nt) bv[nt] = bias[bn + wx * 64 + nt * 16 + lr];
  }
#pragma unroll
  for (int mt = 0; mt < 2; ++mt)
#pragma unroll
    for (int nt = 0; nt < 4; ++nt) {
      const int c = bn + wx * 64 + nt * 16 + lr;
#pragma unroll
      for (int i = 0; i < 4; ++i) {
        const int m = bm + wy * 32 + mt * 16 + 4 * lg + i;
        apply_epi<EPI>(acc[mt][nt][i], m, c, N, &bv[nt], res, Cf, Ch, Cl,
                       1.0f);
      }
    }
}

// ---------------- MFMA flash attention (fp16 double-split, 8-wave) -----------
// R22 champion: 512-thread block owns 128 q-rows (8 waves x 16 q-rows).
// K/V staging + barriers amortized over 2x q-rows; LDS 48KB -> 2 blk/CU.
// XCD swizzle b = bid&7.
__global__ __launch_bounds__(512, 2) void flash_mfma(
    const u16* __restrict__ QKVh, const u16* __restrict__ QKVl,
    u16* __restrict__ Oh, u16* __restrict__ Ol) {
  __shared__ __align__(16) u16 KP[2][128][8][8];  // K rows 0-63; P rows 0-127
  __shared__ __align__(16) u16 Vs[2][64][8][8];
  const int tid = threadIdx.x;
  const int w = tid >> 6, lane = tid & 63;
  const int lr = lane & 15, lg = lane >> 4;
  const int bid = blockIdx.x;
  const int b = bid & 7;
  const int slot_b = bid >> 3;  // 0..63
  const int hh = slot_b >> 3;   // 0..7
  const int qt = slot_b & 7;    // 0..7 (128-row q-tiles)

  const u16* Qh = QKVh;
  const u16* Ql = QKVl;
  const u16* Kh = QKVh + 4194304;
  const u16* Kl = QKVl + 4194304;
  const u16* Vh = QKVh + 8388608;
  const u16* Vl = QKVl + 8388608;

  // Q fragments (A-op: m = lr, k-packet = lg), hoisted for all kt
  h8_t qf[2][2];
  {
    size_t g = ((size_t)(b * 1024 + qt * 128 + w * 16 + lr)) * 512 + hh * 64 +
               lg * 8;
    qf[0][0] = *(const h8_t*)&Qh[g];
    qf[0][1] = *(const h8_t*)&Ql[g];
    qf[1][0] = *(const h8_t*)&Qh[g + 32];
    qf[1][1] = *(const h8_t*)&Ql[g + 32];
  }

  f4_t oacc[4];
#pragma unroll
  for (int nt = 0; nt < 4; ++nt) oacc[nt] = (f4_t){0.f, 0.f, 0.f, 0.f};
  float mrun[4], lrun[4];
#pragma unroll
  for (int i = 0; i < 4; ++i) {
    mrun[i] = -__builtin_huge_valf();
    lrun[i] = 0.0f;
  }

  const int rowl8 = lane >> 3, slot8 = lane & 7;  // stage coords (8 rows/chunk)

  for (int kt = 0; kt < 16; ++kt) {
    __syncthreads();  // prior PV done reading Vs + KP(P)
    // ---- stage K tile + Vt tile via global_load_lds: 32 x 1KB chunks,
    //      distributed across 8 waves (2 iters each for K and V) ----
#pragma unroll
    for (int it = 0; it < 2; ++it) {
      const int f = w + 8 * it;  // 0..15
      const int plane = f >> 3, ch = f & 7;
      const int row = ch * 8 + rowl8;
      const int kp = slot8 ^ (row & 7);
      const size_t gk =
          ((size_t)(b * 1024 + kt * 64 + row)) * 512 + hh * 64 + kp * 8;
      if (plane == 0)
        gload16(&Kh[gk], &KP[0][0][0][0] + ch * 512);
      else
        gload16(&Kl[gk], &KP[1][0][0][0] + ch * 512);
    }
#pragma unroll
    for (int it = 0; it < 2; ++it) {
      const int f = w + 8 * it;  // 0..15
      const int plane = f >> 3, ch = f & 7;
      const int row = ch * 8 + rowl8;
      const int kp = slot8 ^ (row & 7);
      const size_t gv =
          ((size_t)((b * 8 + hh) * 64 + row)) * 1024 + kt * 64 + kp * 8;
      if (plane == 0)
        gload16(&Vh[gv], &Vs[0][0][0][0] + ch * 512);
      else
        gload16(&Vl[gv], &Vs[1][0][0][0] + ch * 512);
    }
    __syncthreads();

    // ---- S = Q K^T : 4 n-tiles x 2 k-slices x 3 products ----
    f4_t s[4];
#pragma unroll
    for (int nt = 0; nt < 4; ++nt) {
      s[nt] = (f4_t){0.f, 0.f, 0.f, 0.f};
      const int col = nt * 16 + lr;
#pragma unroll
      for (int ks = 0; ks < 2; ++ks) {
        int slt = (ks * 4 + lg) ^ (col & 7);
        h8_t kh = *(const h8_t*)&KP[0][col][slt][0];
        h8_t kl = *(const h8_t*)&KP[1][col][slt][0];
        s[nt] = prod3(qf[ks][0], qf[ks][1], kh, kl, s[nt]);
      }
    }

    // ---- online softmax (row = 4*lg+i; reduce over lr via shfl) ----
#pragma unroll
    for (int i = 0; i < 4; ++i) {
      float rm = -__builtin_huge_valf();
#pragma unroll
      for (int nt = 0; nt < 4; ++nt) {
        s[nt][i] *= 0.125f;
        rm = fmaxf(rm, s[nt][i]);
      }
      rm = fmaxf(rm, __shfl_xor(rm, 1));
      rm = fmaxf(rm, __shfl_xor(rm, 2));
      rm = fmaxf(rm, __shfl_xor(rm, 4));
      rm = fmaxf(rm, __shfl_xor(rm, 8));
      float mnew = fmaxf(mrun[i], rm);
      float alpha = __expf(mrun[i] - mnew);
      float rs = 0.0f;
#pragma unroll
      for (int nt = 0; nt < 4; ++nt) {
        float p = __expf(s[nt][i] - mnew);
        s[nt][i] = p;
        rs += p;
      }
      rs += __shfl_xor(rs, 1);
      rs += __shfl_xor(rs, 2);
      rs += __shfl_xor(rs, 4);
      rs += __shfl_xor(rs, 8);
      lrun[i] = lrun[i] * alpha + rs;
      mrun[i] = mnew;
#pragma unroll
      for (int nt = 0; nt < 4; ++nt) oacc[nt][i] *= alpha;
    }

    __syncthreads();  // all waves done reading K tile -> safe to overwrite

    // ---- P -> KP (wave-private rows 0..127, 2 planes, swizzled) ----
#pragma unroll
    for (int nt = 0; nt < 4; ++nt)
#pragma unroll
      for (int i = 0; i < 4; ++i) {
        int qrow = w * 16 + 4 * lg + i;
        int kv = nt * 16 + lr;
        int kp = kv >> 3, j = kv & 7;
        int slt = kp ^ (qrow & 7);
        u16 h2, l2;
        split2(s[nt][i], h2, l2);
        KP[0][qrow][slt][j] = h2;
        KP[1][qrow][slt][j] = l2;
      }

    // ---- O += P V (A = own P rows, B = Vt cols) ----
    h8_t pf[2][2];
#pragma unroll
    for (int ks = 0; ks < 2; ++ks) {
      int row = w * 16 + lr;
      int slt = (ks * 4 + lg) ^ (row & 7);
      pf[ks][0] = *(const h8_t*)&KP[0][row][slt][0];
      pf[ks][1] = *(const h8_t*)&KP[1][row][slt][0];
    }
#pragma unroll
    for (int ntd = 0; ntd < 4; ++ntd) {
      const int col = ntd * 16 + lr;
#pragma unroll
      for (int ks = 0; ks < 2; ++ks) {
        int slt = (ks * 4 + lg) ^ (col & 7);
        h8_t vh = *(const h8_t*)&Vs[0][col][slt][0];
        h8_t vl = *(const h8_t*)&Vs[1][col][slt][0];
        oacc[ntd] = prod3(pf[ks][0], pf[ks][1], vh, vl, oacc[ntd]);
      }
    }
  }

  // ---- epilogue: normalize, split2, store planes [B,T,512] ----
#pragma unroll
  for (int i = 0; i < 4; ++i) {
    float inv = 1.0f / lrun[i];
    int t = qt * 128 + w * 16 + 4 * lg + i;
#pragma unroll
    for (int ntd = 0; ntd < 4; ++ntd) {
      int d = hh * 64 + ntd * 16 + lr;
      size_t idx = ((size_t)(b * 1024 + t)) * 512 + d;
      u16 h2, l2;
      split2(oacc[ntd][i] * inv, h2, l2);
      Oh[idx] = h2;
      Ol[idx] = l2;
    }
  }
}

// ---------------- row kernels ----------------
DEV float wave_sum(float v) {
#pragma unroll
  for (int off = 1; off < 64; off <<= 1) v += __shfl_xor(v, off);
  return v;
}

DEV void store8_split2(u16* H, u16* L, size_t base, const float* t) {
  u16 vh[8], vl[8];
#pragma unroll
  for (int j = 0; j < 8; ++j) split2(t[j], vh[j], vl[j]);
  *(ushort4*)&H[base] = make_ushort4(vh[0], vh[1], vh[2], vh[3]);
  *(ushort4*)&H[base + 4] = make_ushort4(vh[4], vh[5], vh[6], vh[7]);
  *(ushort4*)&L[base] = make_ushort4(vl[0], vl[1], vl[2], vl[3]);
  *(ushort4*)&L[base + 4] = make_ushort4(vl[4], vl[5], vl[6], vl[7]);
}

__global__ __launch_bounds__(256) void ln_split2(const float* __restrict__ x,
                                                 const float* __restrict__ g,
                                                 const float* __restrict__ b,
                                                 u16* __restrict__ yh,
                                                 u16* __restrict__ yl) {
  const int row = blockIdx.x * 4 + (threadIdx.x >> 6);
  const int lane = threadIdx.x & 63;
  const float* xr = x + (size_t)row * DMODEL;
  float v[8];
  *(float4*)&v[0] = *(const float4*)(xr + lane * 8);
  *(float4*)&v[4] = *(const float4*)(xr + lane * 8 + 4);
  float s = 0.0f;
#pragma unroll
  for (int j = 0; j < 8; ++j) s += v[j];
  s = wave_sum(s);
  float mean = s * (1.0f / 512.0f);
  float s2 = 0.0f;
#pragma unroll
  for (int j = 0; j < 8; ++j) {
    float d = v[j] - mean;
    s2 += d * d;
  }
  s2 = wave_sum(s2);
  float rstd = 1.0f / sqrtf(s2 * (1.0f / 512.0f) + 1e-5f);
  float gg[8], bv[8];
  *(float4*)&gg[0] = *(const float4*)(g + lane * 8);
  *(float4*)&gg[4] = *(const float4*)(g + lane * 8 + 4);
  *(float4*)&bv[0] = *(const float4*)(b + lane * 8);
  *(float4*)&bv[4] = *(const float4*)(b + lane * 8 + 4);
  float t[8];
#pragma unroll
  for (int j = 0; j < 8; ++j) t[j] = (v[j] - mean) * rstd * gg[j] + bv[j];
  store8_split2(yh, yl, (size_t)row * DMODEL + lane * 8, t);
}

// LN + l2norm -> 2 fp16 planes (VQ head Q)
__global__ __launch_bounds__(256) void ln_l2_split2(
    const float* __restrict__ x, const float* __restrict__ g,
    const float* __restrict__ b, u16* __restrict__ yh, u16* __restrict__ yl) {
  const int row = blockIdx.x * 4 + (threadIdx.x >> 6);
  const int lane = threadIdx.x & 63;
  const float* xr = x + (size_t)row * DMODEL;
  float v[8];
  *(float4*)&v[0] = *(const float4*)(xr + lane * 8);
  *(float4*)&v[4] = *(const float4*)(xr + lane * 8 + 4);
  float s = 0.0f;
#pragma unroll
  for (int j = 0; j < 8; ++j) s += v[j];
  s = wave_sum(s);
  float mean = s * (1.0f / 512.0f);
  float s2 = 0.0f;
#pragma unroll
  for (int j = 0; j < 8; ++j) {
    float d = v[j] - mean;
    s2 += d * d;
  }
  s2 = wave_sum(s2);
  float rstd = 1.0f / sqrtf(s2 * (1.0f / 512.0f) + 1e-5f);
  float gg[8], bv[8];
  *(float4*)&gg[0] = *(const float4*)(g + lane * 8);
  *(float4*)&gg[4] = *(const float4*)(g + lane * 8 + 4);
  *(float4*)&bv[0] = *(const float4*)(b + lane * 8);
  *(float4*)&bv[4] = *(const float4*)(b + lane * 8 + 4);
  float t[8];
#pragma unroll
  for (int j = 0; j < 8; ++j) t[j] = (v[j] - mean) * rstd * gg[j] + bv[j];
  float n2 = 0.0f;
#pragma unroll
  for (int j = 0; j < 8; ++j) n2 += t[j] * t[j];
  n2 = wave_sum(n2);
  float den = fmaxf(sqrtf(n2), 1e-12f);
#pragma unroll
  for (int j = 0; j < 8; ++j) t[j] /= den;
  store8_split2(yh, yl, (size_t)row * DMODEL + lane * 8, t);
}

__global__ __launch_bounds__(256) void l2_split2(const float* __restrict__ x,
                                                 u16* __restrict__ yh,
                                                 u16* __restrict__ yl) {
  const int row = blockIdx.x * 4 + (threadIdx.x >> 6);
  const int lane = threadIdx.x & 63;
  const float* xr = x + (size_t)row * DMODEL;
  float v[8];
  *(float4*)&v[0] = *(const float4*)(xr + lane * 8);
  *(float4*)&v[4] = *(const float4*)(xr + lane * 8 + 4);
  float n2 = 0.0f;
#pragma unroll
  for (int j = 0; j < 8; ++j) n2 += v[j] * v[j];
  n2 = wave_sum(n2);
  float den = fmaxf(sqrtf(n2), 1e-12f);
#pragma unroll
  for (int j = 0; j < 8; ++j) v[j] /= den;
  store8_split2(yh, yl, (size_t)row * DMODEL + lane * 8, v);
}

// softmax over rows of 1024, in-place on 2 fp16 planes
__global__ __launch_bounds__(256) void softmax2(u16* __restrict__ H,
                                                u16* __restrict__ L) {
  const int row = blockIdx.x;
  const int tid = threadIdx.x;
  const size_t base = (size_t)row * 1024 + tid * 4;
  ushort4 qh = *(const ushort4*)&H[base];
  ushort4 ql = *(const ushort4*)&L[base];
  float v0 = h2f(qh.x) + h2f(ql.x);
  float v1 = h2f(qh.y) + h2f(ql.y);
  float v2 = h2f(qh.z) + h2f(ql.z);
  float v3 = h2f(qh.w) + h2f(ql.w);
  float mx = fmaxf(fmaxf(v0, v1), fmaxf(v2, v3));
#pragma unroll
  for (int off = 1; off < 64; off <<= 1) mx = fmaxf(mx, __shfl_xor(mx, off));
  __shared__ float red[4];
  const int wv = tid >> 6;
  if ((tid & 63) == 0) red[wv] = mx;
  __syncthreads();
  mx = fmaxf(fmaxf(red[0], red[1]), fmaxf(red[2], red[3]));
  float e0 = __expf(v0 - mx), e1 = __expf(v1 - mx), e2 = __expf(v2 - mx),
        e3 = __expf(v3 - mx);
  float s = e0 + e1 + e2 + e3;
#pragma unroll
  for (int off = 1; off < 64; off <<= 1) s += __shfl_xor(s, off);
  __syncthreads();
  if ((tid & 63) == 0) red[wv] = s;
  __syncthreads();
  s = red[0] + red[1] + red[2] + red[3];
  float inv = 1.0f / s;
  u16 ah[4], al[4];
  split2(e0 * inv, ah[0], al[0]);
  split2(e1 * inv, ah[1], al[1]);
  split2(e2 * inv, ah[2], al[2]);
  split2(e3 * inv, ah[3], al[3]);
  *(ushort4*)&H[base] = make_ushort4(ah[0], ah[1], ah[2], ah[3]);
  *(ushort4*)&L[base] = make_ushort4(al[0], al[1], al[2], al[3]);
}

// generic fp32 -> 2 fp16 planes splitter (n4 = n/4)
__global__ __launch_bounds__(256) void split2_k(const float* __restrict__ src,
                                                u16* __restrict__ H,
                                                u16* __restrict__ L, int n4) {
  for (int e = blockIdx.x * 256 + threadIdx.x; e < n4; e += gridDim.x * 256) {
    float4 v = *(const float4*)(src + (size_t)e * 4);
    u16 ah[4], al[4];
    split2(v.x, ah[0], al[0]);
    split2(v.y, ah[1], al[1]);
    split2(v.z, ah[2], al[2]);
    split2(v.w, ah[3], al[3]);
    *(ushort4*)&H[(size_t)e * 4] = make_ushort4(ah[0], ah[1], ah[2], ah[3]);
    *(ushort4*)&L[(size_t)e * 4] = make_ushort4(al[0], al[1], al[2], al[3]);
  }
}

// transpose codebook [1024][512] -> cbT [512][1024], split into 2 planes
__global__ __launch_bounds__(256) void tsplit_cb(const float* __restrict__ cb,
                                                 u16* __restrict__ th,
                                                 u16* __restrict__ tl) {
  const int c = blockIdx.x;
  const int t = threadIdx.x;
  u16 ah[4], al[4];
#pragma unroll
  for (int j = 0; j < 4; ++j) {
    float v = cb[(size_t)(4 * t + j) * 512 + c];
    split2(v, ah[j], al[j]);
  }
  const size_t base = (size_t)c * 1024 + 4 * t;
  *(ushort4*)&th[base] = make_ushort4(ah[0], ah[1], ah[2], ah[3]);
  *(ushort4*)&tl[base] = make_ushort4(al[0], al[1], al[2], al[3]);
}

__global__ __launch_bounds__(256) void vq_finalize(
    const float* __restrict__ logits, const float* __restrict__ patterns,
    float* __restrict__ emb, float* __restrict__ assign,
    float* __restrict__ idxf) {
  const int row = blockIdx.x * 4 + (threadIdx.x >> 6);
  const int lane = threadIdx.x & 63;
  const float* lr = logits + (size_t)row * NPAT;
  float best = -__builtin_huge_valf();
  int bi = 0;
#pragma unroll
  for (int jj = 0; jj < 8; ++jj) {
    int j = lane + jj * 64;
    float v = lr[j];
    if (v > best) {
      best = v;
      bi = j;
    }
  }
#pragma unroll
  for (int off = 1; off < 64; off <<= 1) {
    float ob = __shfl_xor(best, off);
    int oi = __shfl_xor(bi, off);
    if (ob > best || (ob == best && oi < bi)) {
      best = ob;
      bi = oi;
    }
  }
  const float* pr = patterns + (size_t)bi * DMODEL;
#pragma unroll
  for (int g = 0; g < 2; ++g) {
    int c = lane * 8 + g * 4;
    float4 pv = *(const float4*)(pr + c);
    *(float4*)(emb + (size_t)row * DMODEL + c) = pv;
    float4 av;
    av.x = (c + 0 == bi) ? 1.0f : 0.0f;
    av.y = (c + 1 == bi) ? 1.0f : 0.0f;
    av.z = (c + 2 == bi) ? 1.0f : 0.0f;
    av.w = (c + 3 == bi) ? 1.0f : 0.0f;
    *(float4*)(assign + (size_t)row * NPAT + c) = av;
  }
  if (lane == 0) idxf[row] = (float)bi;
}

// ---------------- host launch ----------------
extern "C" void kernel_launch(void* const* d_in, const int* in_sizes, int n_in,
                              void* d_out, int out_size, void* d_ws,
                              size_t ws_size, hipStream_t stream) {
  (void)in_sizes;
  (void)n_in;
  (void)out_size;
  (void)ws_size;
  const float* x = (const float*)d_in[0];
  const float* gumbel = (const float*)d_in[1];
  const float* sym_w = (const float*)d_in[2];
  const float* sym_b = (const float*)d_in[3];
  const float* codebook = (const float*)d_in[4];
  const float* pos_enc = (const float*)d_in[5];
  const float* attn_in_w = (const float*)d_in[6];
  const float* attn_in_b = (const float*)d_in[7];
  const float* attn_out_w = (const float*)d_in[8];
  const float* attn_out_b = (const float*)d_in[9];
  const float* n1_g = (const float*)d_in[10];
  const float* n1_b = (const float*)d_in[11];
  const float* n2_g = (const float*)d_in[12];
  const float* n2_b = (const float*)d_in[13];
  const float* ffn_w1 = (const float*)d_in[14];
  const float* ffn_b1 = (const float*)d_in[15];
  const float* ffn_w2 = (const float*)d_in[16];
  const float* ffn_b2 = (const float*)d_in[17];
  const float* q_w = (const float*)d_in[18];
  const float* q_b = (const float*)d_in[19];
  const float* qln_g = (const float*)d_in[20];
  const float* qln_b = (const float*)d_in[21];
  const float* patterns = (const float*)d_in[22];
  const int* epoch = (const int*)d_in[23];
  const int* tot = (const int*)d_in[24];

  float* out = (float*)d_out;
  float* emb = out;               // [8192,512]
  float* assign = out + 4194304;  // [8192,512]
  float* logits = out + 8388608;  // [8192,512]
  float* h = out + 12582912;      // [8192,512]
  float* idxf = out + 16777216;   // [8192]

  float* ws_f = (float*)d_ws;
  // A region @0 (18.87M floats = 37.75M u16)
  u16* a16 = (u16*)ws_f;
  // B region @18.87M floats (6.29M floats = 12.58M u16)
  float* bF = ws_f + 18874368;
  u16* b16 = (u16*)bF;
  u16 *hnH = b16, *hnL = b16 + 4194304;
  // W region @25.17M floats (2.36M u16 capacity)
  float* wF = ws_f + 25165824;
  u16* w16 = (u16*)wF;

  // ---- symbolization ----
  u16 *xH = a16, *xL = a16 + 8388608;
  split2_k<<<2048, 256, 0, stream>>>(x, xH, xL, 2097152);
  split2_k<<<512, 256, 0, stream>>>(sym_w, w16, w16 + 524288, 131072);
  gemm_mf<64, E_BIAS><<<512, 256, 0, stream>>>(
      xH, xL, w16, w16 + 524288, sym_b, nullptr, bF, nullptr, nullptr, 512,
      1024, 1024, 1024, 4, nullptr, nullptr);
  l2_split2<<<256, 256, 0, stream>>>(codebook, w16, w16 + 524288);
  u16 *hpH = a16, *hpL = a16 + 4194304;
  l2_split2<<<2048, 256, 0, stream>>>(bF, hpH, hpL);
  u16 *sH = a16 + 12582912, *sL = a16 + 20971520;
  // gum: N=1024 -> 8-wave BN=256, grid 128*4=512
  gemm_mf8<E_GUM2><<<512, 512, 0, stream>>>(hpH, hpL, w16, w16 + 524288,
                                            nullptr, gumbel, nullptr, sH, sL,
                                            1024, 512, 512, 512, 4);
  softmax2<<<8192, 256, 0, stream>>>(sH, sL);
  tsplit_cb<<<512, 256, 0, stream>>>(codebook, w16, w16 + 524288);
  gemm_mf<64, E_POS><<<512, 256, 0, stream>>>(
      sH, sL, w16, w16 + 524288, nullptr, pos_enc, h, nullptr, nullptr, 512,
      1024, 1024, 1024, 4, nullptr, nullptr);

  // ---- transformer layers ----
  u16 *qkvH = a16, *qkvL = a16 + 12582912;
  u16* w1p = a16 + 33554432;            // 2 x 1048576 u16 (after qkv/mid)
  u16* w2p = b16 + 8388608;             // 2 x 1048576 u16 (after hn planes)
  u16 *pH = a16, *pL = a16 + 16777216;  // FFN mid [8192,2048] x2 planes

  for (int l = 0; l < 4; ++l) {
    const float* inw = attn_in_w + (size_t)l * 1536 * 512;
    const float* inb = attn_in_b + (size_t)l * 1536;
    const float* outw = attn_out_w + (size_t)l * 512 * 512;
    const float* outb = attn_out_b + (size_t)l * 512;
    const float* w1 = ffn_w1 + (size_t)l * 2048 * 512;
    const float* b1 = ffn_b1 + (size_t)l * 2048;
    const float* w2 = ffn_w2 + (size_t)l * 512 * 2048;
    const float* b2 = ffn_b2 + (size_t)l * 512;

    ln_split2<<<2048, 256, 0, stream>>>(h, n1_g + l * 512, n1_b + l * 512,
                                        hnH, hnL);
    split2_k<<<1024, 256, 0, stream>>>(inw, w16, w16 + 786432, 196608);
    // qkv: N=1536 -> 8-wave BN=256, grid 128*6=768
    gemm_mf8<E_QKV2><<<768, 512, 0, stream>>>(hnH, hnL, w16, w16 + 786432,
                                              inb, nullptr, nullptr, qkvH,
                                              qkvL, 1536, 512, 512, 512, 6);
    // flash: 8-wave, 128 q-rows/block, grid 512
    flash_mfma<<<512, 512, 0, stream>>>(qkvH, qkvL, hnH, hnL);
    split2_k<<<256, 256, 0, stream>>>(outw, w16, w16 + 262144, 65536);
    gemm_mf<64, E_RES><<<512, 256, 0, stream>>>(
        hnH, hnL, w16, w16 + 262144, outb, h, h, nullptr, nullptr, 512, 512,
        512, 512, 4, nullptr, nullptr);
    ln_split2<<<2048, 256, 0, stream>>>(h, n2_g + l * 512, n2_b + l * 512,
                                        hnH, hnL);
    split2_k<<<1024, 256, 0, stream>>>(w1, w1p, w1p + 1048576, 262144);
    split2_k<<<1024, 256, 0, stream>>>(w2, w2p, w2p + 1048576, 262144);
    // GELU: N=2048 -> 8-wave BN=256, grid 128*8=1024
    gemm_mf8<E_GELU2><<<1024, 512, 0, stream>>>(hnH, hnL, w1p, w1p + 1048576,
                                                b1, nullptr, nullptr, pH, pL,
                                                2048, 512, 512, 512, 8);
    // w2: single K=2048 GEMM with residual (BM=64 -> 512 blocks, 4 blk/CU)
    gemm_mf<64, E_RES><<<512, 256, 0, stream>>>(
        pH, pL, w2p, w2p + 1048576, b2, h, h, nullptr, nullptr, 512, 2048,
        2048, 2048, 4, nullptr, nullptr);
  }

  // ---- VQ head (MFMA fp16 double-split) ----
  u16 *hsH = a16, *hsL = a16 + 4194304;             // h planes
  u16 *QpH = a16 + 8388608, *QpL = a16 + 12582912;  // Q planes
  split2_k<<<1024, 256, 0, stream>>>(h, hsH, hsL, 1048576);
  split2_k<<<256, 256, 0, stream>>>(q_w, w16, w16 + 262144, 65536);
  gemm_mf<64, E_BIAS><<<512, 256, 0, stream>>>(
      hsH, hsL, w16, w16 + 262144, q_b, nullptr, bF, nullptr, nullptr, 512,
      512, 512, 512, 4, nullptr, nullptr);
  ln_l2_split2<<<2048, 256, 0, stream>>>(bF, qln_g, qln_b, QpH, QpL);
  l2_split2<<<128, 256, 0, stream>>>(patterns, w16 + 524288, w16 + 786432);
  gemm_mf<64, E_VQ><<<512, 256, 0, stream>>>(
      QpH, QpL, w16 + 524288, w16 + 786432, nullptr, nullptr, logits, nullptr,
      nullptr, 512, 512, 512, 512, 4, epoch, tot);
  vq_finalize<<<2048, 256, 0, stream>>>(logits, patterns, emb, assign, idxf);
}

// Round 24
// 1563.783 us; speedup vs baseline: 1.2658x; 1.2658x over previous
//
#include <hip/hip_runtime.h>

#define DEV __device__ __forceinline__

typedef unsigned short u16;
typedef unsigned int u32;
typedef __attribute__((ext_vector_type(8))) _Float16 h8_t;  // 8 f16 (4 VGPR)
typedef __attribute__((ext_vector_type(4))) float f4_t;

constexpr int T_SEQ = 1024;
constexpr int DMODEL = 512;
constexpr int NPAT = 512;

// ---------------- epilogue modes ----------------
enum {
  E_BIAS = 0,
  E_VQ = 5,
  E_RES = 6,
  E_POS = 8,
  E_GUM2 = 9,
  E_GELU2 = 10,
  E_QKV2 = 11
};

// ---------------- fp16 double-split helpers (err ~2^-22, fp32-grade) ---------
DEV float h2f(u16 h) { return (float)__builtin_bit_cast(_Float16, h); }
DEV void split2(float x, u16& h, u16& l) {
  _Float16 hh = (_Float16)x;
  float r = x - (float)hh;
  _Float16 ll = (_Float16)r;
  h = __builtin_bit_cast(u16, hh);
  l = __builtin_bit_cast(u16, ll);
}

DEV f4_t mfh(h8_t a, h8_t b, f4_t c) {
  return __builtin_amdgcn_mfma_f32_16x16x32_f16(a, b, c, 0, 0, 0);
}
// 3-product double-split accumulate: AB = AhBh + AhBl + AlBh (+O(2^-22))
DEV f4_t prod3(h8_t ah, h8_t al, h8_t bh, h8_t bl, f4_t c) {
  c = mfh(ah, bh, c);
  c = mfh(ah, bl, c);
  c = mfh(al, bh, c);
  return c;
}

// async global->LDS, 16B per lane; LDS dest = base + lane*16 (wave-uniform base)
typedef const __attribute__((address_space(1))) unsigned char* gas_t;
typedef __attribute__((address_space(3))) unsigned char* las_t;
DEV void gload16(const u16* g, u16* l) {
  __builtin_amdgcn_global_load_lds((gas_t)(const void*)g, (las_t)(void*)l, 16,
                                   0, 0);
}

// shared epilogue applier (C frag: col = lane&15, row = 4*(lane>>4)+i)
template <int EPI>
DEV void apply_epi(float v, int m, int c, int N, const float* bias_v,
                   const float* res, float* Cf, u16* Ch, u16* Cl, float invt) {
  const size_t idx = (size_t)m * N + c;
  if constexpr (EPI == E_BIAS) {
    Cf[idx] = v + bias_v[0];
  } else if constexpr (EPI == E_VQ) {
    Cf[idx] = v * invt;
  } else if constexpr (EPI == E_RES) {
    Cf[idx] = v + bias_v[0] + res[idx];
  } else if constexpr (EPI == E_POS) {
    Cf[idx] = v + res[(size_t)(m & 1023) * N + c];
  } else if constexpr (EPI == E_GUM2) {
    float t = 4.0f * v + 2.0f * res[idx];
    u16 h2, l2;
    split2(t, h2, l2);
    Ch[idx] = h2;
    Cl[idx] = l2;
  } else if constexpr (EPI == E_GELU2) {
    float t = v + bias_v[0];
    float g = 0.5f * t * (1.0f + erff(t * 0.7071067811865476f));
    u16 h2, l2;
    split2(g, h2, l2);
    Ch[idx] = h2;
    Cl[idx] = l2;
  } else if constexpr (EPI == E_QKV2) {
    float t = v + bias_v[0];
    u16 h2, l2;
    split2(t, h2, l2);
    size_t o;
    if (c < 512) {
      o = (size_t)m * 512 + c;                    // Q [B,T,512]
    } else if (c < 1024) {
      o = 4194304 + (size_t)m * 512 + (c - 512);  // K [B,T,512]
    } else {
      int cc = c - 1024, hh2 = cc >> 6, dd = cc & 63;
      int bb2 = m >> 10, tt2 = m & 1023;
      o = 8388608 + (((size_t)(bb2 * 8 + hh2) * 64 + dd) << 10) + tt2;  // Vt
    }
    Ch[o] = h2;
    Cl[o] = l2;
  }
}

// ---------------- MFMA GEMM, fp16 double-split (fp32-accurate) ---------------
// 4-wave BM=64 x BN=128 (champion; measured optimum for N=512-class GEMMs).
// BM {32,64,128} x occupancy mapped R18/R19: 64 is the peak. R23's A-in-reg
// variant regressed (barrier vmcnt-drain serializes register prefetch).
template <int BM, int EPI>
__global__ __launch_bounds__(256, BM == 64 ? 3 : 2) void gemm_mf(
    const u16* __restrict__ Ah, const u16* __restrict__ Al,
    const u16* __restrict__ Bh, const u16* __restrict__ Bl,
    const float* __restrict__ bias, const float* __restrict__ res,
    float* __restrict__ Cf, u16* __restrict__ Ch, u16* __restrict__ Cl, int N,
    int KK, int lda, int ldb, int gx, const int* __restrict__ ep,
    const int* __restrict__ tot) {
  constexpr int MT = BM / 32;
  constexpr int CPP = BM / 16;
  __shared__ __align__(16) u16 AsH[2][BM][4][8], AsL[2][BM][4][8];
  __shared__ __align__(16) u16 BsH[2][128][4][8], BsL[2][128][4][8];
  const int tid = threadIdx.x;
  const int w = tid >> 6, lane = tid & 63;
  const int wy = w >> 1, wx = w & 1;
  const int lr = lane & 15, lg = lane >> 4;

  const int nwg = gridDim.x;
  const int bid = blockIdx.x;
  const int qq = nwg >> 3;
  const int wg = (bid & 7) * qq + (bid >> 3);
  const int by = wg / gx, bx = wg % gx;
  const int bm = by * BM, bn = bx * 128;

  const int rowl = lane >> 2, slot4 = lane & 3;

  auto STAGE = [&](int k0, int buf) {
#pragma unroll
    for (int it = 0; it < CPP / 2; ++it) {
      const int f = w + 4 * it;
      const int plane = f / CPP;
      const int ch = f % CPP;
      const int row = ch * 16 + rowl;
      const int kp = slot4 ^ ((row >> 1) & 3);
      const size_t g = (size_t)(bm + row) * lda + k0 + kp * 8;
      if (plane == 0)
        gload16(&Ah[g], &AsH[buf][0][0][0] + ch * 512);
      else
        gload16(&Al[g], &AsL[buf][0][0][0] + ch * 512);
    }
#pragma unroll
    for (int it = 0; it < 4; ++it) {
      const int f = w + 4 * it;
      const int plane = f >> 3;
      const int ch = f & 7;
      const int row = ch * 16 + rowl;
      const int kp = slot4 ^ ((row >> 1) & 3);
      const size_t g = (size_t)(bn + row) * ldb + k0 + kp * 8;
      if (plane == 0)
        gload16(&Bh[g], &BsH[buf][0][0][0] + ch * 512);
      else
        gload16(&Bl[g], &BsL[buf][0][0][0] + ch * 512);
    }
  };

  f4_t acc[MT][4];
#pragma unroll
  for (int mt = 0; mt < MT; ++mt)
#pragma unroll
    for (int nt = 0; nt < 4; ++nt) acc[mt][nt] = (f4_t){0.f, 0.f, 0.f, 0.f};

  const int nsteps = KK / 32;
  STAGE(0, 0);
  __syncthreads();
  for (int t = 0; t < nsteps; ++t) {
    const int cur = t & 1;
    if (t + 1 < nsteps) STAGE((t + 1) * 32, cur ^ 1);

    h8_t fah[MT], fal[MT], fbh[4], fbl[4];
#pragma unroll
    for (int mt = 0; mt < MT; ++mt) {
      int row = wy * (BM / 2) + mt * 16 + lr;
      int slot = lg ^ ((row >> 1) & 3);
      fah[mt] = *(const h8_t*)&AsH[cur][row][slot][0];
      fal[mt] = *(const h8_t*)&AsL[cur][row][slot][0];
    }
#pragma unroll
    for (int nt = 0; nt < 4; ++nt) {
      int col = wx * 64 + nt * 16 + lr;
      int slot = lg ^ ((col >> 1) & 3);
      fbh[nt] = *(const h8_t*)&BsH[cur][col][slot][0];
      fbl[nt] = *(const h8_t*)&BsL[cur][col][slot][0];
    }
#pragma unroll
    for (int mt = 0; mt < MT; ++mt)
#pragma unroll
      for (int nt = 0; nt < 4; ++nt)
        acc[mt][nt] = prod3(fah[mt], fal[mt], fbh[nt], fbl[nt], acc[mt][nt]);
    __syncthreads();
  }

  float bv[4];
  if constexpr (EPI == E_BIAS || EPI == E_RES || EPI == E_GELU2 ||
                EPI == E_QKV2) {
#pragma unroll
    for (int nt = 0; nt < 4; ++nt) bv[nt] = bias[bn + wx * 64 + nt * 16 + lr];
  }
  float invt = 1.0f;
  if constexpr (EPI == E_VQ) {
    float tt = 1.0f - 0.5f * (float)ep[0] / (float)tot[0];
    invt = 1.0f / fmaxf(0.5f, tt);
  }
#pragma unroll
  for (int mt = 0; mt < MT; ++mt)
#pragma unroll
    for (int nt = 0; nt < 4; ++nt) {
      const int c = bn + wx * 64 + nt * 16 + lr;
#pragma unroll
      for (int i = 0; i < 4; ++i) {
        const int m = bm + wy * (BM / 2) + mt * 16 + 4 * lg + i;
        apply_epi<EPI>(acc[mt][nt][i], m, c, N, &bv[nt], res, Cf, Ch, Cl,
                       invt);
      }
    }
}

// ---------------- 8-wave MFMA GEMM: BM=64 x BN=256, 512 threads --------------
// Per-wave tile identical to gemm_mf<64>; 2x4 wave grid. LDS dbuf 80KB ->
// 2 blk/CU = 16 waves/CU AND staged-bytes/FLOP improves. N>=1024 GEMMs.
// Validated R21 (-30us total).
template <int EPI>
__global__ __launch_bounds__(512, 2) void gemm_mf8(
    const u16* __restrict__ Ah, const u16* __restrict__ Al,
    const u16* __restrict__ Bh, const u16* __restrict__ Bl,
    const float* __restrict__ bias, const float* __restrict__ res,
    float* __restrict__ Cf, u16* __restrict__ Ch, u16* __restrict__ Cl, int N,
    int KK, int lda, int ldb, int gx) {
  __shared__ __align__(16) u16 AsH[2][64][4][8], AsL[2][64][4][8];
  __shared__ __align__(16) u16 BsH[2][256][4][8], BsL[2][256][4][8];
  const int tid = threadIdx.x;
  const int w = tid >> 6, lane = tid & 63;
  const int wy = w >> 2, wx = w & 3;  // 2x4 wave grid
  const int lr = lane & 15, lg = lane >> 4;

  const int nwg = gridDim.x;
  const int bid = blockIdx.x;
  const int qq = nwg >> 3;
  const int wg = (bid & 7) * qq + (bid >> 3);
  const int by = wg / gx, bx = wg % gx;
  const int bm = by * 64, bn = bx * 256;

  const int rowl = lane >> 2, slot4 = lane & 3;

  auto STAGE = [&](int k0, int buf) {
#pragma unroll
    for (int it = 0; it < 5; ++it) {
      const int f = w + 8 * it;  // 0..39
      if (f < 8) {
        const int plane = f >> 2, ch = f & 3;
        const int row = ch * 16 + rowl;
        const int kp = slot4 ^ ((row >> 1) & 3);
        const size_t g = (size_t)(bm + row) * lda + k0 + kp * 8;
        if (plane == 0)
          gload16(&Ah[g], &AsH[buf][0][0][0] + ch * 512);
        else
          gload16(&Al[g], &AsL[buf][0][0][0] + ch * 512);
      } else {
        const int fb = f - 8;  // 0..31
        const int plane = fb >> 4, ch = fb & 15;
        const int row = ch * 16 + rowl;
        const int kp = slot4 ^ ((row >> 1) & 3);
        const size_t g = (size_t)(bn + row) * ldb + k0 + kp * 8;
        if (plane == 0)
          gload16(&Bh[g], &BsH[buf][0][0][0] + ch * 512);
        else
          gload16(&Bl[g], &BsL[buf][0][0][0] + ch * 512);
      }
    }
  };

  f4_t acc[2][4];
#pragma unroll
  for (int mt = 0; mt < 2; ++mt)
#pragma unroll
    for (int nt = 0; nt < 4; ++nt) acc[mt][nt] = (f4_t){0.f, 0.f, 0.f, 0.f};

  const int nsteps = KK / 32;
  STAGE(0, 0);
  __syncthreads();
  for (int t = 0; t < nsteps; ++t) {
    const int cur = t & 1;
    if (t + 1 < nsteps) STAGE((t + 1) * 32, cur ^ 1);

    h8_t fah[2], fal[2], fbh[4], fbl[4];
#pragma unroll
    for (int mt = 0; mt < 2; ++mt) {
      int row = wy * 32 + mt * 16 + lr;
      int slot = lg ^ ((row >> 1) & 3);
      fah[mt] = *(const h8_t*)&AsH[cur][row][slot][0];
      fal[mt] = *(const h8_t*)&AsL[cur][row][slot][0];
    }
#pragma unroll
    for (int nt = 0; nt < 4; ++nt) {
      int col = wx * 64 + nt * 16 + lr;
      int slot = lg ^ ((col >> 1) & 3);
      fbh[nt] = *(const h8_t*)&BsH[cur][col][slot][0];
      fbl[nt] = *(const h8_t*)&BsL[cur][col][slot][0];
    }
#pragma unroll
    for (int mt = 0; mt < 2; ++mt)
#pragma unroll
      for (int nt = 0; nt < 4; ++nt)
        acc[mt][nt] = prod3(fah[mt], fal[mt], fbh[nt], fbl[nt], acc[mt][nt]);
    __syncthreads();
  }

  float bv[4];
  if constexpr (EPI == E_BIAS || EPI == E_RES || EPI == E_GELU2 ||
                EPI == E_QKV2) {
#pragma unroll
    for (int nt = 0; nt < 4; ++nt) bv[nt] = bias[bn + wx * 64 + nt * 16 + lr];
  }
#pragma unroll
  for (int mt = 0; mt < 2; ++mt)
#pragma unroll
    for (int nt = 0; nt < 4; ++nt) {
      const int c = bn + wx * 64 + nt * 16 + lr;
#pragma unroll
      for (int i = 0; i < 4; ++i) {
        const int m = bm + wy * 32 + mt * 16 + 4 * lg + i;
        apply_epi<EPI>(acc[mt][nt][i], m, c, N, &bv[nt], res, Cf, Ch, Cl,
                       1.0f);
      }
    }
}

// ---------------- MFMA flash attention (fp16 double-split, 8-wave) -----------
// gemm_mf8 mechanism applied to flash: 512-thread block owns 128 q-rows
// (8 waves x 16 q-rows, per-wave state identical to R15 flash -> ~64 VGPR).
// K/V staging + barriers amortized over 2x q-rows; LDS 48KB (KP[2][128]:
// K in rows 0-63, P all 128; Vs 16KB) -> grid 512 = 2 blk/CU x 8 waves
// = 16 waves/CU (occupancy unchanged vs champion, intensity doubled).
// XCD swizzle b = bid&7.
__global__ __launch_bounds__(512, 2) void flash_mfma(
    const u16* __restrict__ QKVh, const u16* __restrict__ QKVl,
    u16* __restrict__ Oh, u16* __restrict__ Ol) {
  __shared__ __align__(16) u16 KP[2][128][8][8];  // K rows 0-63; P rows 0-127
  __shared__ __align__(16) u16 Vs[2][64][8][8];
  const int tid = threadIdx.x;
  const int w = tid >> 6, lane = tid & 63;
  const int lr = lane & 15, lg = lane >> 4;
  const int bid = blockIdx.x;
  const int b = bid & 7;
  const int slot_b = bid >> 3;  // 0..63
  const int hh = slot_b >> 3;   // 0..7
  const int qt = slot_b & 7;    // 0..7 (128-row q-tiles)

  const u16* Qh = QKVh;
  const u16* Ql = QKVl;
  const u16* Kh = QKVh + 4194304;
  const u16* Kl = QKVl + 4194304;
  const u16* Vh = QKVh + 8388608;
  const u16* Vl = QKVl + 8388608;

  // Q fragments (A-op: m = lr, k-packet = lg), hoisted for all kt
  h8_t qf[2][2];
  {
    size_t g = ((size_t)(b * 1024 + qt * 128 + w * 16 + lr)) * 512 + hh * 64 +
               lg * 8;
    qf[0][0] = *(const h8_t*)&Qh[g];
    qf[0][1] = *(const h8_t*)&Ql[g];
    qf[1][0] = *(const h8_t*)&Qh[g + 32];
    qf[1][1] = *(const h8_t*)&Ql[g + 32];
  }

  f4_t oacc[4];
#pragma unroll
  for (int nt = 0; nt < 4; ++nt) oacc[nt] = (f4_t){0.f, 0.f, 0.f, 0.f};
  float mrun[4], lrun[4];
#pragma unroll
  for (int i = 0; i < 4; ++i) {
    mrun[i] = -__builtin_huge_valf();
    lrun[i] = 0.0f;
  }

  const int rowl8 = lane >> 3, slot8 = lane & 7;  // stage coords (8 rows/chunk)

  for (int kt = 0; kt < 16; ++kt) {
    __syncthreads();  // prior PV done reading Vs + KP(P)
    // ---- stage K tile + Vt tile via global_load_lds: 32 x 1KB chunks,
    //      distributed across 8 waves (2 iters each for K and V) ----
#pragma unroll
    for (int it = 0; it < 2; ++it) {
      const int f = w + 8 * it;  // 0..15
      const int plane = f >> 3, ch = f & 7;
      const int row = ch * 8 + rowl8;
      const int kp = slot8 ^ (row & 7);
      const size_t gk =
          ((size_t)(b * 1024 + kt * 64 + row)) * 512 + hh * 64 + kp * 8;
      if (plane == 0)
        gload16(&Kh[gk], &KP[0][0][0][0] + ch * 512);
      else
        gload16(&Kl[gk], &KP[1][0][0][0] + ch * 512);
    }
#pragma unroll
    for (int it = 0; it < 2; ++it) {
      const int f = w + 8 * it;  // 0..15
      const int plane = f >> 3, ch = f & 7;
      const int row = ch * 8 + rowl8;
      const int kp = slot8 ^ (row & 7);
      const size_t gv =
          ((size_t)((b * 8 + hh) * 64 + row)) * 1024 + kt * 64 + kp * 8;
      if (plane == 0)
        gload16(&Vh[gv], &Vs[0][0][0][0] + ch * 512);
      else
        gload16(&Vl[gv], &Vs[1][0][0][0] + ch * 512);
    }
    __syncthreads();

    // ---- S = Q K^T : 4 n-tiles x 2 k-slices x 3 products ----
    f4_t s[4];
#pragma unroll
    for (int nt = 0; nt < 4; ++nt) {
      s[nt] = (f4_t){0.f, 0.f, 0.f, 0.f};
      const int col = nt * 16 + lr;
#pragma unroll
      for (int ks = 0; ks < 2; ++ks) {
        int slt = (ks * 4 + lg) ^ (col & 7);
        h8_t kh = *(const h8_t*)&KP[0][col][slt][0];
        h8_t kl = *(const h8_t*)&KP[1][col][slt][0];
        s[nt] = prod3(qf[ks][0], qf[ks][1], kh, kl, s[nt]);
      }
    }

    // ---- online softmax (row = 4*lg+i; reduce over lr via shfl) ----
#pragma unroll
    for (int i = 0; i < 4; ++i) {
      float rm = -__builtin_huge_valf();
#pragma unroll
      for (int nt = 0; nt < 4; ++nt) {
        s[nt][i] *= 0.125f;
        rm = fmaxf(rm, s[nt][i]);
      }
      rm = fmaxf(rm, __shfl_xor(rm, 1));
      rm = fmaxf(rm, __shfl_xor(rm, 2));
      rm = fmaxf(rm, __shfl_xor(rm, 4));
      rm = fmaxf(rm, __shfl_xor(rm, 8));
      float mnew = fmaxf(mrun[i], rm);
      float alpha = __expf(mrun[i] - mnew);
      float rs = 0.0f;
#pragma unroll
      for (int nt = 0; nt < 4; ++nt) {
        float p = __expf(s[nt][i] - mnew);
        s[nt][i] = p;
        rs += p;
      }
      rs += __shfl_xor(rs, 1);
      rs += __shfl_xor(rs, 2);
      rs += __shfl_xor(rs, 4);
      rs += __shfl_xor(rs, 8);
      lrun[i] = lrun[i] * alpha + rs;
      mrun[i] = mnew;
#pragma unroll
      for (int nt = 0; nt < 4; ++nt) oacc[nt][i] *= alpha;
    }

    __syncthreads();  // all waves done reading K tile -> safe to overwrite

    // ---- P -> KP (wave-private rows 0..127, 2 planes, swizzled) ----
#pragma unroll
    for (int nt = 0; nt < 4; ++nt)
#pragma unroll
      for (int i = 0; i < 4; ++i) {
        int qrow = w * 16 + 4 * lg + i;
        int kv = nt * 16 + lr;
        int kp = kv >> 3, j = kv & 7;
        int slt = kp ^ (qrow & 7);
        u16 h2, l2;
        split2(s[nt][i], h2, l2);
        KP[0][qrow][slt][j] = h2;
        KP[1][qrow][slt][j] = l2;
      }

    // ---- O += P V (A = own P rows, B = Vt cols) ----
    h8_t pf[2][2];
#pragma unroll
    for (int ks = 0; ks < 2; ++ks) {
      int row = w * 16 + lr;
      int slt = (ks * 4 + lg) ^ (row & 7);
      pf[ks][0] = *(const h8_t*)&KP[0][row][slt][0];
      pf[ks][1] = *(const h8_t*)&KP[1][row][slt][0];
    }
#pragma unroll
    for (int ntd = 0; ntd < 4; ++ntd) {
      const int col = ntd * 16 + lr;
#pragma unroll
      for (int ks = 0; ks < 2; ++ks) {
        int slt = (ks * 4 + lg) ^ (col & 7);
        h8_t vh = *(const h8_t*)&Vs[0][col][slt][0];
        h8_t vl = *(const h8_t*)&Vs[1][col][slt][0];
        oacc[ntd] = prod3(pf[ks][0], pf[ks][1], vh, vl, oacc[ntd]);
      }
    }
  }

  // ---- epilogue: normalize, split2, store planes [B,T,512] ----
#pragma unroll
  for (int i = 0; i < 4; ++i) {
    float inv = 1.0f / lrun[i];
    int t = qt * 128 + w * 16 + 4 * lg + i;
#pragma unroll
    for (int ntd = 0; ntd < 4; ++ntd) {
      int d = hh * 64 + ntd * 16 + lr;
      size_t idx = ((size_t)(b * 1024 + t)) * 512 + d;
      u16 h2, l2;
      split2(oacc[ntd][i] * inv, h2, l2);
      Oh[idx] = h2;
      Ol[idx] = l2;
    }
  }
}

// ---------------- row kernels ----------------
DEV float wave_sum(float v) {
#pragma unroll
  for (int off = 1; off < 64; off <<= 1) v += __shfl_xor(v, off);
  return v;
}

DEV void store8_split2(u16* H, u16* L, size_t base, const float* t) {
  u16 vh[8], vl[8];
#pragma unroll
  for (int j = 0; j < 8; ++j) split2(t[j], vh[j], vl[j]);
  *(ushort4*)&H[base] = make_ushort4(vh[0], vh[1], vh[2], vh[3]);
  *(ushort4*)&H[base + 4] = make_ushort4(vh[4], vh[5], vh[6], vh[7]);
  *(ushort4*)&L[base] = make_ushort4(vl[0], vl[1], vl[2], vl[3]);
  *(ushort4*)&L[base + 4] = make_ushort4(vl[4], vl[5], vl[6], vl[7]);
}

__global__ __launch_bounds__(256) void ln_split2(const float* __restrict__ x,
                                                 const float* __restrict__ g,
                                                 const float* __restrict__ b,
                                                 u16* __restrict__ yh,
                                                 u16* __restrict__ yl) {
  const int row = blockIdx.x * 4 + (threadIdx.x >> 6);
  const int lane = threadIdx.x & 63;
  const float* xr = x + (size_t)row * DMODEL;
  float v[8];
  *(float4*)&v[0] = *(const float4*)(xr + lane * 8);
  *(float4*)&v[4] = *(const float4*)(xr + lane * 8 + 4);
  float s = 0.0f;
#pragma unroll
  for (int j = 0; j < 8; ++j) s += v[j];
  s = wave_sum(s);
  float mean = s * (1.0f / 512.0f);
  float s2 = 0.0f;
#pragma unroll
  for (int j = 0; j < 8; ++j) {
    float d = v[j] - mean;
    s2 += d * d;
  }
  s2 = wave_sum(s2);
  float rstd = 1.0f / sqrtf(s2 * (1.0f / 512.0f) + 1e-5f);
  float gg[8], bv[8];
  *(float4*)&gg[0] = *(const float4*)(g + lane * 8);
  *(float4*)&gg[4] = *(const float4*)(g + lane * 8 + 4);
  *(float4*)&bv[0] = *(const float4*)(b + lane * 8);
  *(float4*)&bv[4] = *(const float4*)(b + lane * 8 + 4);
  float t[8];
#pragma unroll
  for (int j = 0; j < 8; ++j) t[j] = (v[j] - mean) * rstd * gg[j] + bv[j];
  store8_split2(yh, yl, (size_t)row * DMODEL + lane * 8, t);
}

// LN + l2norm -> 2 fp16 planes (VQ head Q)
__global__ __launch_bounds__(256) void ln_l2_split2(
    const float* __restrict__ x, const float* __restrict__ g,
    const float* __restrict__ b, u16* __restrict__ yh, u16* __restrict__ yl) {
  const int row = blockIdx.x * 4 + (threadIdx.x >> 6);
  const int lane = threadIdx.x & 63;
  const float* xr = x + (size_t)row * DMODEL;
  float v[8];
  *(float4*)&v[0] = *(const float4*)(xr + lane * 8);
  *(float4*)&v[4] = *(const float4*)(xr + lane * 8 + 4);
  float s = 0.0f;
#pragma unroll
  for (int j = 0; j < 8; ++j) s += v[j];
  s = wave_sum(s);
  float mean = s * (1.0f / 512.0f);
  float s2 = 0.0f;
#pragma unroll
  for (int j = 0; j < 8; ++j) {
    float d = v[j] - mean;
    s2 += d * d;
  }
  s2 = wave_sum(s2);
  float rstd = 1.0f / sqrtf(s2 * (1.0f / 512.0f) + 1e-5f);
  float gg[8], bv[8];
  *(float4*)&gg[0] = *(const float4*)(g + lane * 8);
  *(float4*)&gg[4] = *(const float4*)(g + lane * 8 + 4);
  *(float4*)&bv[0] = *(const float4*)(b + lane * 8);
  *(float4*)&bv[4] = *(const float4*)(b + lane * 8 + 4);
  float t[8];
#pragma unroll
  for (int j = 0; j < 8; ++j) t[j] = (v[j] - mean) * rstd * gg[j] + bv[j];
  float n2 = 0.0f;
#pragma unroll
  for (int j = 0; j < 8; ++j) n2 += t[j] * t[j];
  n2 = wave_sum(n2);
  float den = fmaxf(sqrtf(n2), 1e-12f);
#pragma unroll
  for (int j = 0; j < 8; ++j) t[j] /= den;
  store8_split2(yh, yl, (size_t)row * DMODEL + lane * 8, t);
}

__global__ __launch_bounds__(256) void l2_split2(const float* __restrict__ x,
                                                 u16* __restrict__ yh,
                                                 u16* __restrict__ yl) {
  const int row = blockIdx.x * 4 + (threadIdx.x >> 6);
  const int lane = threadIdx.x & 63;
  const float* xr = x + (size_t)row * DMODEL;
  float v[8];
  *(float4*)&v[0] = *(const float4*)(xr + lane * 8);
  *(float4*)&v[4] = *(const float4*)(xr + lane * 8 + 4);
  float n2 = 0.0f;
#pragma unroll
  for (int j = 0; j < 8; ++j) n2 += v[j] * v[j];
  n2 = wave_sum(n2);
  float den = fmaxf(sqrtf(n2), 1e-12f);
#pragma unroll
  for (int j = 0; j < 8; ++j) v[j] /= den;
  store8_split2(yh, yl, (size_t)row * DMODEL + lane * 8, v);
}

// softmax over rows of 1024, in-place on 2 fp16 planes
__global__ __launch_bounds__(256) void softmax2(u16* __restrict__ H,
                                                u16* __restrict__ L) {
  const int row = blockIdx.x;
  const int tid = threadIdx.x;
  const size_t base = (size_t)row * 1024 + tid * 4;
  ushort4 qh = *(const ushort4*)&H[base];
  ushort4 ql = *(const ushort4*)&L[base];
  float v0 = h2f(qh.x) + h2f(ql.x);
  float v1 = h2f(qh.y) + h2f(ql.y);
  float v2 = h2f(qh.z) + h2f(ql.z);
  float v3 = h2f(qh.w) + h2f(ql.w);
  float mx = fmaxf(fmaxf(v0, v1), fmaxf(v2, v3));
#pragma unroll
  for (int off = 1; off < 64; off <<= 1) mx = fmaxf(mx, __shfl_xor(mx, off));
  __shared__ float red[4];
  const int wv = tid >> 6;
  if ((tid & 63) == 0) red[wv] = mx;
  __syncthreads();
  mx = fmaxf(fmaxf(red[0], red[1]), fmaxf(red[2], red[3]));
  float e0 = __expf(v0 - mx), e1 = __expf(v1 - mx), e2 = __expf(v2 - mx),
        e3 = __expf(v3 - mx);
  float s = e0 + e1 + e2 + e3;
#pragma unroll
  for (int off = 1; off < 64; off <<= 1) s += __shfl_xor(s, off);
  __syncthreads();
  if ((tid & 63) == 0) red[wv] = s;
  __syncthreads();
  s = red[0] + red[1] + red[2] + red[3];
  float inv = 1.0f / s;
  u16 ah[4], al[4];
  split2(e0 * inv, ah[0], al[0]);
  split2(e1 * inv, ah[1], al[1]);
  split2(e2 * inv, ah[2], al[2]);
  split2(e3 * inv, ah[3], al[3]);
  *(ushort4*)&H[base] = make_ushort4(ah[0], ah[1], ah[2], ah[3]);
  *(ushort4*)&L[base] = make_ushort4(al[0], al[1], al[2], al[3]);
}

// generic fp32 -> 2 fp16 planes splitter (n4 = n/4)
__global__ __launch_bounds__(256) void split2_k(const float* __restrict__ src,
                                                u16* __restrict__ H,
                                                u16* __restrict__ L, int n4) {
  for (int e = blockIdx.x * 256 + threadIdx.x; e < n4; e += gridDim.x * 256) {
    float4 v = *(const float4*)(src + (size_t)e * 4);
    u16 ah[4], al[4];
    split2(v.x, ah[0], al[0]);
    split2(v.y, ah[1], al[1]);
    split2(v.z, ah[2], al[2]);
    split2(v.w, ah[3], al[3]);
    *(ushort4*)&H[(size_t)e * 4] = make_ushort4(ah[0], ah[1], ah[2], ah[3]);
    *(ushort4*)&L[(size_t)e * 4] = make_ushort4(al[0], al[1], al[2], al[3]);
  }
}

// transpose codebook [1024][512] -> cbT [512][1024], split into 2 planes
__global__ __launch_bounds__(256) void tsplit_cb(const float* __restrict__ cb,
                                                 u16* __restrict__ th,
                                                 u16* __restrict__ tl) {
  const int c = blockIdx.x;
  const int t = threadIdx.x;
  u16 ah[4], al[4];
#pragma unroll
  for (int j = 0; j < 4; ++j) {
    float v = cb[(size_t)(4 * t + j) * 512 + c];
    split2(v, ah[j], al[j]);
  }
  const size_t base = (size_t)c * 1024 + 4 * t;
  *(ushort4*)&th[base] = make_ushort4(ah[0], ah[1], ah[2], ah[3]);
  *(ushort4*)&tl[base] = make_ushort4(al[0], al[1], al[2], al[3]);
}

__global__ __launch_bounds__(256) void vq_finalize(
    const float* __restrict__ logits, const float* __restrict__ patterns,
    float* __restrict__ emb, float* __restrict__ assign,
    float* __restrict__ idxf) {
  const int row = blockIdx.x * 4 + (threadIdx.x >> 6);
  const int lane = threadIdx.x & 63;
  const float* lr = logits + (size_t)row * NPAT;
  float best = -__builtin_huge_valf();
  int bi = 0;
#pragma unroll
  for (int jj = 0; jj < 8; ++jj) {
    int j = lane + jj * 64;
    float v = lr[j];
    if (v > best) {
      best = v;
      bi = j;
    }
  }
#pragma unroll
  for (int off = 1; off < 64; off <<= 1) {
    float ob = __shfl_xor(best, off);
    int oi = __shfl_xor(bi, off);
    if (ob > best || (ob == best && oi < bi)) {
      best = ob;
      bi = oi;
    }
  }
  const float* pr = patterns + (size_t)bi * DMODEL;
#pragma unroll
  for (int g = 0; g < 2; ++g) {
    int c = lane * 8 + g * 4;
    float4 pv = *(const float4*)(pr + c);
    *(float4*)(emb + (size_t)row * DMODEL + c) = pv;
    float4 av;
    av.x = (c + 0 == bi) ? 1.0f : 0.0f;
    av.y = (c + 1 == bi) ? 1.0f : 0.0f;
    av.z = (c + 2 == bi) ? 1.0f : 0.0f;
    av.w = (c + 3 == bi) ? 1.0f : 0.0f;
    *(float4*)(assign + (size_t)row * NPAT + c) = av;
  }
  if (lane == 0) idxf[row] = (float)bi;
}

// ---------------- host launch ----------------
extern "C" void kernel_launch(void* const* d_in, const int* in_sizes, int n_in,
                              void* d_out, int out_size, void* d_ws,
                              size_t ws_size, hipStream_t stream) {
  (void)in_sizes;
  (void)n_in;
  (void)out_size;
  (void)ws_size;
  const float* x = (const float*)d_in[0];
  const float* gumbel = (const float*)d_in[1];
  const float* sym_w = (const float*)d_in[2];
  const float* sym_b = (const float*)d_in[3];
  const float* codebook = (const float*)d_in[4];
  const float* pos_enc = (const float*)d_in[5];
  const float* attn_in_w = (const float*)d_in[6];
  const float* attn_in_b = (const float*)d_in[7];
  const float* attn_out_w = (const float*)d_in[8];
  const float* attn_out_b = (const float*)d_in[9];
  const float* n1_g = (const float*)d_in[10];
  const float* n1_b = (const float*)d_in[11];
  const float* n2_g = (const float*)d_in[12];
  const float* n2_b = (const float*)d_in[13];
  const float* ffn_w1 = (const float*)d_in[14];
  const float* ffn_b1 = (const float*)d_in[15];
  const float* ffn_w2 = (const float*)d_in[16];
  const float* ffn_b2 = (const float*)d_in[17];
  const float* q_w = (const float*)d_in[18];
  const float* q_b = (const float*)d_in[19];
  const float* qln_g = (const float*)d_in[20];
  const float* qln_b = (const float*)d_in[21];
  const float* patterns = (const float*)d_in[22];
  const int* epoch = (const int*)d_in[23];
  const int* tot = (const int*)d_in[24];

  float* out = (float*)d_out;
  float* emb = out;               // [8192,512]
  float* assign = out + 4194304;  // [8192,512]
  float* logits = out + 8388608;  // [8192,512]
  float* h = out + 12582912;      // [8192,512]
  float* idxf = out + 16777216;   // [8192]

  float* ws_f = (float*)d_ws;
  // A region @0 (18.87M floats = 37.75M u16)
  u16* a16 = (u16*)ws_f;
  // B region @18.87M floats (6.29M floats = 12.58M u16)
  float* bF = ws_f + 18874368;
  u16* b16 = (u16*)bF;
  u16 *hnH = b16, *hnL = b16 + 4194304;
  // W region @25.17M floats (2.36M u16 capacity)
  float* wF = ws_f + 25165824;
  u16* w16 = (u16*)wF;

  // ---- symbolization ----
  u16 *xH = a16, *xL = a16 + 8388608;
  split2_k<<<2048, 256, 0, stream>>>(x, xH, xL, 2097152);
  split2_k<<<512, 256, 0, stream>>>(sym_w, w16, w16 + 524288, 131072);
  gemm_mf<64, E_BIAS><<<512, 256, 0, stream>>>(
      xH, xL, w16, w16 + 524288, sym_b, nullptr, bF, nullptr, nullptr, 512,
      1024, 1024, 1024, 4, nullptr, nullptr);
  l2_split2<<<256, 256, 0, stream>>>(codebook, w16, w16 + 524288);
  u16 *hpH = a16, *hpL = a16 + 4194304;
  l2_split2<<<2048, 256, 0, stream>>>(bF, hpH, hpL);
  u16 *sH = a16 + 12582912, *sL = a16 + 20971520;
  // gum: N=1024 -> 8-wave BN=256, grid 128*4=512
  gemm_mf8<E_GUM2><<<512, 512, 0, stream>>>(hpH, hpL, w16, w16 + 524288,
                                            nullptr, gumbel, nullptr, sH, sL,
                                            1024, 512, 512, 512, 4);
  softmax2<<<8192, 256, 0, stream>>>(sH, sL);
  tsplit_cb<<<512, 256, 0, stream>>>(codebook, w16, w16 + 524288);
  gemm_mf<64, E_POS><<<512, 256, 0, stream>>>(
      sH, sL, w16, w16 + 524288, nullptr, pos_enc, h, nullptr, nullptr, 512,
      1024, 1024, 1024, 4, nullptr, nullptr);

  // ---- transformer layers ----
  u16 *qkvH = a16, *qkvL = a16 + 12582912;
  u16* w1p = a16 + 33554432;            // 2 x 1048576 u16 (after qkv/mid)
  u16* w2p = b16 + 8388608;             // 2 x 1048576 u16 (after hn planes)
  u16 *pH = a16, *pL = a16 + 16777216;  // FFN mid [8192,2048] x2 planes

  for (int l = 0; l < 4; ++l) {
    const float* inw = attn_in_w + (size_t)l * 1536 * 512;
    const float* inb = attn_in_b + (size_t)l * 1536;
    const float* outw = attn_out_w + (size_t)l * 512 * 512;
    const float* outb = attn_out_b + (size_t)l * 512;
    const float* w1 = ffn_w1 + (size_t)l * 2048 * 512;
    const float* b1 = ffn_b1 + (size_t)l * 2048;
    const float* w2 = ffn_w2 + (size_t)l * 512 * 2048;
    const float* b2 = ffn_b2 + (size_t)l * 512;

    ln_split2<<<2048, 256, 0, stream>>>(h, n1_g + l * 512, n1_b + l * 512,
                                        hnH, hnL);
    split2_k<<<1024, 256, 0, stream>>>(inw, w16, w16 + 786432, 196608);
    // qkv: N=1536 -> 8-wave BN=256, grid 128*6=768
    gemm_mf8<E_QKV2><<<768, 512, 0, stream>>>(hnH, hnL, w16, w16 + 786432,
                                              inb, nullptr, nullptr, qkvH,
                                              qkvL, 1536, 512, 512, 512, 6);
    // flash: 8-wave, 128 q-rows/block, grid 512
    flash_mfma<<<512, 512, 0, stream>>>(qkvH, qkvL, hnH, hnL);
    split2_k<<<256, 256, 0, stream>>>(outw, w16, w16 + 262144, 65536);
    gemm_mf<64, E_RES><<<512, 256, 0, stream>>>(
        hnH, hnL, w16, w16 + 262144, outb, h, h, nullptr, nullptr, 512, 512,
        512, 512, 4, nullptr, nullptr);
    ln_split2<<<2048, 256, 0, stream>>>(h, n2_g + l * 512, n2_b + l * 512,
                                        hnH, hnL);
    split2_k<<<1024, 256, 0, stream>>>(w1, w1p, w1p + 1048576, 262144);
    split2_k<<<1024, 256, 0, stream>>>(w2, w2p, w2p + 1048576, 262144);
    // GELU: N=2048 -> 8-wave BN=256, grid 128*8=1024
    gemm_mf8<E_GELU2><<<1024, 512, 0, stream>>>(hnH, hnL, w1p, w1p + 1048576,
                                                b1, nullptr, nullptr, pH, pL,
                                                2048, 512, 512, 512, 8);
    // w2: single K=2048 GEMM with residual (BM=64 -> 512 blocks, 3 blk/CU)
    gemm_mf<64, E_RES><<<512, 256, 0, stream>>>(
        pH, pL, w2p, w2p + 1048576, b2, h, h, nullptr, nullptr, 512, 2048,
        2048, 2048, 4, nullptr, nullptr);
  }

  // ---- VQ head (MFMA fp16 double-split) ----
  u16 *hsH = a16, *hsL = a16 + 4194304;             // h planes
  u16 *QpH = a16 + 8388608, *QpL = a16 + 12582912;  // Q planes
  split2_k<<<1024, 256, 0, stream>>>(h, hsH, hsL, 1048576);
  split2_k<<<256, 256, 0, stream>>>(q_w, w16, w16 + 262144, 65536);
  gemm_mf<64, E_BIAS><<<512, 256, 0, stream>>>(
      hsH, hsL, w16, w16 + 262144, q_b, nullptr, bF, nullptr, nullptr, 512,
      512, 512, 512, 4, nullptr, nullptr);
  ln_l2_split2<<<2048, 256, 0, stream>>>(bF, qln_g, qln_b, QpH, QpL);
  l2_split2<<<128, 256, 0, stream>>>(patterns, w16 + 524288, w16 + 786432);
  gemm_mf<64, E_VQ><<<512, 256, 0, stream>>>(
      QpH, QpL, w16 + 524288, w16 + 786432, nullptr, nullptr, logits, nullptr,
      nullptr, 512, 512, 512, 512, 4, epoch, tot);
  vq_finalize<<<2048, 256, 0, stream>>>(logits, patterns, emb, assign, idxf);
}

// Round 25
// 1546.003 us; speedup vs baseline: 1.2803x; 1.0115x over previous
//
#include <hip/hip_runtime.h>

#define DEV __device__ __forceinline__

typedef unsigned short u16;
typedef unsigned int u32;
typedef __attribute__((ext_vector_type(8))) _Float16 h8_t;  // 8 f16 (4 VGPR)
typedef __attribute__((ext_vector_type(4))) float f4_t;

constexpr int T_SEQ = 1024;
constexpr int DMODEL = 512;
constexpr int NPAT = 512;

// ---------------- epilogue modes ----------------
enum {
  E_BIAS = 0,
  E_VQ = 5,
  E_RES = 6,
  E_POS = 8,
  E_GUM2 = 9,
  E_GELU2 = 10,
  E_QKV2 = 11,
  E_RES2 = 12  // E_RES + split2 planes out (fuses downstream split2_k)
};

// ---------------- fp16 double-split helpers (err ~2^-22, fp32-grade) ---------
DEV float h2f(u16 h) { return (float)__builtin_bit_cast(_Float16, h); }
DEV void split2(float x, u16& h, u16& l) {
  _Float16 hh = (_Float16)x;
  float r = x - (float)hh;
  _Float16 ll = (_Float16)r;
  h = __builtin_bit_cast(u16, hh);
  l = __builtin_bit_cast(u16, ll);
}

DEV f4_t mfh(h8_t a, h8_t b, f4_t c) {
  return __builtin_amdgcn_mfma_f32_16x16x32_f16(a, b, c, 0, 0, 0);
}
// 3-product double-split accumulate: AB = AhBh + AhBl + AlBh (+O(2^-22))
DEV f4_t prod3(h8_t ah, h8_t al, h8_t bh, h8_t bl, f4_t c) {
  c = mfh(ah, bh, c);
  c = mfh(ah, bl, c);
  c = mfh(al, bh, c);
  return c;
}

// async global->LDS, 16B per lane; LDS dest = base + lane*16 (wave-uniform base)
typedef const __attribute__((address_space(1))) unsigned char* gas_t;
typedef __attribute__((address_space(3))) unsigned char* las_t;
DEV void gload16(const u16* g, u16* l) {
  __builtin_amdgcn_global_load_lds((gas_t)(const void*)g, (las_t)(void*)l, 16,
                                   0, 0);
}

// shared epilogue applier (C frag: col = lane&15, row = 4*(lane>>4)+i)
template <int EPI>
DEV void apply_epi(float v, int m, int c, int N, const float* bias_v,
                   const float* res, float* Cf, u16* Ch, u16* Cl, float invt) {
  const size_t idx = (size_t)m * N + c;
  if constexpr (EPI == E_BIAS) {
    Cf[idx] = v + bias_v[0];
  } else if constexpr (EPI == E_VQ) {
    Cf[idx] = v * invt;
  } else if constexpr (EPI == E_RES) {
    Cf[idx] = v + bias_v[0] + res[idx];
  } else if constexpr (EPI == E_RES2) {
    float t = v + bias_v[0] + res[idx];
    Cf[idx] = t;
    u16 h2, l2;
    split2(t, h2, l2);
    Ch[idx] = h2;
    Cl[idx] = l2;
  } else if constexpr (EPI == E_POS) {
    Cf[idx] = v + res[(size_t)(m & 1023) * N + c];
  } else if constexpr (EPI == E_GUM2) {
    float t = 4.0f * v + 2.0f * res[idx];
    u16 h2, l2;
    split2(t, h2, l2);
    Ch[idx] = h2;
    Cl[idx] = l2;
  } else if constexpr (EPI == E_GELU2) {
    float t = v + bias_v[0];
    float g = 0.5f * t * (1.0f + erff(t * 0.7071067811865476f));
    u16 h2, l2;
    split2(g, h2, l2);
    Ch[idx] = h2;
    Cl[idx] = l2;
  } else if constexpr (EPI == E_QKV2) {
    float t = v + bias_v[0];
    u16 h2, l2;
    split2(t, h2, l2);
    size_t o;
    if (c < 512) {
      o = (size_t)m * 512 + c;                    // Q [B,T,512]
    } else if (c < 1024) {
      o = 4194304 + (size_t)m * 512 + (c - 512);  // K [B,T,512]
    } else {
      int cc = c - 1024, hh2 = cc >> 6, dd = cc & 63;
      int bb2 = m >> 10, tt2 = m & 1023;
      o = 8388608 + (((size_t)(bb2 * 8 + hh2) * 64 + dd) << 10) + tt2;  // Vt
    }
    Ch[o] = h2;
    Cl[o] = l2;
  }
}

// ---------------- MFMA GEMM, fp16 double-split (fp32-accurate) ---------------
// 4-wave BM=64 x BN=128 (champion; measured optimum for N=512-class GEMMs).
// BM {32,64,128} x occupancy mapped R18/R19: 64 is the peak. R23's A-in-reg
// variant regressed (barrier vmcnt-drain serializes register prefetch).
template <int BM, int EPI>
__global__ __launch_bounds__(256, BM == 64 ? 3 : 2) void gemm_mf(
    const u16* __restrict__ Ah, const u16* __restrict__ Al,
    const u16* __restrict__ Bh, const u16* __restrict__ Bl,
    const float* __restrict__ bias, const float* __restrict__ res,
    float* __restrict__ Cf, u16* __restrict__ Ch, u16* __restrict__ Cl, int N,
    int KK, int lda, int ldb, int gx, const int* __restrict__ ep,
    const int* __restrict__ tot) {
  constexpr int MT = BM / 32;
  constexpr int CPP = BM / 16;
  __shared__ __align__(16) u16 AsH[2][BM][4][8], AsL[2][BM][4][8];
  __shared__ __align__(16) u16 BsH[2][128][4][8], BsL[2][128][4][8];
  const int tid = threadIdx.x;
  const int w = tid >> 6, lane = tid & 63;
  const int wy = w >> 1, wx = w & 1;
  const int lr = lane & 15, lg = lane >> 4;

  const int nwg = gridDim.x;
  const int bid = blockIdx.x;
  const int qq = nwg >> 3;
  const int wg = (bid & 7) * qq + (bid >> 3);
  const int by = wg / gx, bx = wg % gx;
  const int bm = by * BM, bn = bx * 128;

  const int rowl = lane >> 2, slot4 = lane & 3;

  auto STAGE = [&](int k0, int buf) {
#pragma unroll
    for (int it = 0; it < CPP / 2; ++it) {
      const int f = w + 4 * it;
      const int plane = f / CPP;
      const int ch = f % CPP;
      const int row = ch * 16 + rowl;
      const int kp = slot4 ^ ((row >> 1) & 3);
      const size_t g = (size_t)(bm + row) * lda + k0 + kp * 8;
      if (plane == 0)
        gload16(&Ah[g], &AsH[buf][0][0][0] + ch * 512);
      else
        gload16(&Al[g], &AsL[buf][0][0][0] + ch * 512);
    }
#pragma unroll
    for (int it = 0; it < 4; ++it) {
      const int f = w + 4 * it;
      const int plane = f >> 3;
      const int ch = f & 7;
      const int row = ch * 16 + rowl;
      const int kp = slot4 ^ ((row >> 1) & 3);
      const size_t g = (size_t)(bn + row) * ldb + k0 + kp * 8;
      if (plane == 0)
        gload16(&Bh[g], &BsH[buf][0][0][0] + ch * 512);
      else
        gload16(&Bl[g], &BsL[buf][0][0][0] + ch * 512);
    }
  };

  f4_t acc[MT][4];
#pragma unroll
  for (int mt = 0; mt < MT; ++mt)
#pragma unroll
    for (int nt = 0; nt < 4; ++nt) acc[mt][nt] = (f4_t){0.f, 0.f, 0.f, 0.f};

  const int nsteps = KK / 32;
  STAGE(0, 0);
  __syncthreads();
  for (int t = 0; t < nsteps; ++t) {
    const int cur = t & 1;
    if (t + 1 < nsteps) STAGE((t + 1) * 32, cur ^ 1);

    h8_t fah[MT], fal[MT], fbh[4], fbl[4];
#pragma unroll
    for (int mt = 0; mt < MT; ++mt) {
      int row = wy * (BM / 2) + mt * 16 + lr;
      int slot = lg ^ ((row >> 1) & 3);
      fah[mt] = *(const h8_t*)&AsH[cur][row][slot][0];
      fal[mt] = *(const h8_t*)&AsL[cur][row][slot][0];
    }
#pragma unroll
    for (int nt = 0; nt < 4; ++nt) {
      int col = wx * 64 + nt * 16 + lr;
      int slot = lg ^ ((col >> 1) & 3);
      fbh[nt] = *(const h8_t*)&BsH[cur][col][slot][0];
      fbl[nt] = *(const h8_t*)&BsL[cur][col][slot][0];
    }
#pragma unroll
    for (int mt = 0; mt < MT; ++mt)
#pragma unroll
      for (int nt = 0; nt < 4; ++nt)
        acc[mt][nt] = prod3(fah[mt], fal[mt], fbh[nt], fbl[nt], acc[mt][nt]);
    __syncthreads();
  }

  float bv[4];
  if constexpr (EPI == E_BIAS || EPI == E_RES || EPI == E_RES2 ||
                EPI == E_GELU2 || EPI == E_QKV2) {
#pragma unroll
    for (int nt = 0; nt < 4; ++nt) bv[nt] = bias[bn + wx * 64 + nt * 16 + lr];
  }
  float invt = 1.0f;
  if constexpr (EPI == E_VQ) {
    float tt = 1.0f - 0.5f * (float)ep[0] / (float)tot[0];
    invt = 1.0f / fmaxf(0.5f, tt);
  }
#pragma unroll
  for (int mt = 0; mt < MT; ++mt)
#pragma unroll
    for (int nt = 0; nt < 4; ++nt) {
      const int c = bn + wx * 64 + nt * 16 + lr;
#pragma unroll
      for (int i = 0; i < 4; ++i) {
        const int m = bm + wy * (BM / 2) + mt * 16 + 4 * lg + i;
        apply_epi<EPI>(acc[mt][nt][i], m, c, N, &bv[nt], res, Cf, Ch, Cl,
                       invt);
      }
    }
}

// ---------------- 8-wave MFMA GEMM: BM=64 x BN=256, 512 threads --------------
// Per-wave tile identical to gemm_mf<64>; 2x4 wave grid. LDS dbuf 80KB ->
// 2 blk/CU = 16 waves/CU AND staged-bytes/FLOP improves. N>=1024 GEMMs.
// Validated R21 (-30us total).
template <int EPI>
__global__ __launch_bounds__(512, 2) void gemm_mf8(
    const u16* __restrict__ Ah, const u16* __restrict__ Al,
    const u16* __restrict__ Bh, const u16* __restrict__ Bl,
    const float* __restrict__ bias, const float* __restrict__ res,
    float* __restrict__ Cf, u16* __restrict__ Ch, u16* __restrict__ Cl, int N,
    int KK, int lda, int ldb, int gx) {
  __shared__ __align__(16) u16 AsH[2][64][4][8], AsL[2][64][4][8];
  __shared__ __align__(16) u16 BsH[2][256][4][8], BsL[2][256][4][8];
  const int tid = threadIdx.x;
  const int w = tid >> 6, lane = tid & 63;
  const int wy = w >> 2, wx = w & 3;  // 2x4 wave grid
  const int lr = lane & 15, lg = lane >> 4;

  const int nwg = gridDim.x;
  const int bid = blockIdx.x;
  const int qq = nwg >> 3;
  const int wg = (bid & 7) * qq + (bid >> 3);
  const int by = wg / gx, bx = wg % gx;
  const int bm = by * 64, bn = bx * 256;

  const int rowl = lane >> 2, slot4 = lane & 3;

  auto STAGE = [&](int k0, int buf) {
#pragma unroll
    for (int it = 0; it < 5; ++it) {
      const int f = w + 8 * it;  // 0..39
      if (f < 8) {
        const int plane = f >> 2, ch = f & 3;
        const int row = ch * 16 + rowl;
        const int kp = slot4 ^ ((row >> 1) & 3);
        const size_t g = (size_t)(bm + row) * lda + k0 + kp * 8;
        if (plane == 0)
          gload16(&Ah[g], &AsH[buf][0][0][0] + ch * 512);
        else
          gload16(&Al[g], &AsL[buf][0][0][0] + ch * 512);
      } else {
        const int fb = f - 8;  // 0..31
        const int plane = fb >> 4, ch = fb & 15;
        const int row = ch * 16 + rowl;
        const int kp = slot4 ^ ((row >> 1) & 3);
        const size_t g = (size_t)(bn + row) * ldb + k0 + kp * 8;
        if (plane == 0)
          gload16(&Bh[g], &BsH[buf][0][0][0] + ch * 512);
        else
          gload16(&Bl[g], &BsL[buf][0][0][0] + ch * 512);
      }
    }
  };

  f4_t acc[2][4];
#pragma unroll
  for (int mt = 0; mt < 2; ++mt)
#pragma unroll
    for (int nt = 0; nt < 4; ++nt) acc[mt][nt] = (f4_t){0.f, 0.f, 0.f, 0.f};

  const int nsteps = KK / 32;
  STAGE(0, 0);
  __syncthreads();
  for (int t = 0; t < nsteps; ++t) {
    const int cur = t & 1;
    if (t + 1 < nsteps) STAGE((t + 1) * 32, cur ^ 1);

    h8_t fah[2], fal[2], fbh[4], fbl[4];
#pragma unroll
    for (int mt = 0; mt < 2; ++mt) {
      int row = wy * 32 + mt * 16 + lr;
      int slot = lg ^ ((row >> 1) & 3);
      fah[mt] = *(const h8_t*)&AsH[cur][row][slot][0];
      fal[mt] = *(const h8_t*)&AsL[cur][row][slot][0];
    }
#pragma unroll
    for (int nt = 0; nt < 4; ++nt) {
      int col = wx * 64 + nt * 16 + lr;
      int slot = lg ^ ((col >> 1) & 3);
      fbh[nt] = *(const h8_t*)&BsH[cur][col][slot][0];
      fbl[nt] = *(const h8_t*)&BsL[cur][col][slot][0];
    }
#pragma unroll
    for (int mt = 0; mt < 2; ++mt)
#pragma unroll
      for (int nt = 0; nt < 4; ++nt)
        acc[mt][nt] = prod3(fah[mt], fal[mt], fbh[nt], fbl[nt], acc[mt][nt]);
    __syncthreads();
  }

  float bv[4];
  if constexpr (EPI == E_BIAS || EPI == E_RES || EPI == E_RES2 ||
                EPI == E_GELU2 || EPI == E_QKV2) {
#pragma unroll
    for (int nt = 0; nt < 4; ++nt) bv[nt] = bias[bn + wx * 64 + nt * 16 + lr];
  }
#pragma unroll
  for (int mt = 0; mt < 2; ++mt)
#pragma unroll
    for (int nt = 0; nt < 4; ++nt) {
      const int c = bn + wx * 64 + nt * 16 + lr;
#pragma unroll
      for (int i = 0; i < 4; ++i) {
        const int m = bm + wy * 32 + mt * 16 + 4 * lg + i;
        apply_epi<EPI>(acc[mt][nt][i], m, c, N, &bv[nt], res, Cf, Ch, Cl,
                       1.0f);
      }
    }
}

// ---------------- MFMA flash attention (fp16 double-split, 8-wave) -----------
// R22 champion: 512-thread block owns 128 q-rows (8 waves x 16 q-rows).
// K/V staging + barriers amortized over 2x q-rows; LDS 48KB -> 2 blk/CU.
// XCD swizzle b = bid&7.
__global__ __launch_bounds__(512, 2) void flash_mfma(
    const u16* __restrict__ QKVh, const u16* __restrict__ QKVl,
    u16* __restrict__ Oh, u16* __restrict__ Ol) {
  __shared__ __align__(16) u16 KP[2][128][8][8];  // K rows 0-63; P rows 0-127
  __shared__ __align__(16) u16 Vs[2][64][8][8];
  const int tid = threadIdx.x;
  const int w = tid >> 6, lane = tid & 63;
  const int lr = lane & 15, lg = lane >> 4;
  const int bid = blockIdx.x;
  const int b = bid & 7;
  const int slot_b = bid >> 3;  // 0..63
  const int hh = slot_b >> 3;   // 0..7
  const int qt = slot_b & 7;    // 0..7 (128-row q-tiles)

  const u16* Qh = QKVh;
  const u16* Ql = QKVl;
  const u16* Kh = QKVh + 4194304;
  const u16* Kl = QKVl + 4194304;
  const u16* Vh = QKVh + 8388608;
  const u16* Vl = QKVl + 8388608;

  // Q fragments (A-op: m = lr, k-packet = lg), hoisted for all kt
  h8_t qf[2][2];
  {
    size_t g = ((size_t)(b * 1024 + qt * 128 + w * 16 + lr)) * 512 + hh * 64 +
               lg * 8;
    qf[0][0] = *(const h8_t*)&Qh[g];
    qf[0][1] = *(const h8_t*)&Ql[g];
    qf[1][0] = *(const h8_t*)&Qh[g + 32];
    qf[1][1] = *(const h8_t*)&Ql[g + 32];
  }

  f4_t oacc[4];
#pragma unroll
  for (int nt = 0; nt < 4; ++nt) oacc[nt] = (f4_t){0.f, 0.f, 0.f, 0.f};
  float mrun[4], lrun[4];
#pragma unroll
  for (int i = 0; i < 4; ++i) {
    mrun[i] = -__builtin_huge_valf();
    lrun[i] = 0.0f;
  }

  const int rowl8 = lane >> 3, slot8 = lane & 7;  // stage coords (8 rows/chunk)

  for (int kt = 0; kt < 16; ++kt) {
    __syncthreads();  // prior PV done reading Vs + KP(P)
    // ---- stage K tile + Vt tile via global_load_lds: 32 x 1KB chunks,
    //      distributed across 8 waves (2 iters each for K and V) ----
#pragma unroll
    for (int it = 0; it < 2; ++it) {
      const int f = w + 8 * it;  // 0..15
      const int plane = f >> 3, ch = f & 7;
      const int row = ch * 8 + rowl8;
      const int kp = slot8 ^ (row & 7);
      const size_t gk =
          ((size_t)(b * 1024 + kt * 64 + row)) * 512 + hh * 64 + kp * 8;
      if (plane == 0)
        gload16(&Kh[gk], &KP[0][0][0][0] + ch * 512);
      else
        gload16(&Kl[gk], &KP[1][0][0][0] + ch * 512);
    }
#pragma unroll
    for (int it = 0; it < 2; ++it) {
      const int f = w + 8 * it;  // 0..15
      const int plane = f >> 3, ch = f & 7;
      const int row = ch * 8 + rowl8;
      const int kp = slot8 ^ (row & 7);
      const size_t gv =
          ((size_t)((b * 8 + hh) * 64 + row)) * 1024 + kt * 64 + kp * 8;
      if (plane == 0)
        gload16(&Vh[gv], &Vs[0][0][0][0] + ch * 512);
      else
        gload16(&Vl[gv], &Vs[1][0][0][0] + ch * 512);
    }
    __syncthreads();

    // ---- S = Q K^T : 4 n-tiles x 2 k-slices x 3 products ----
    f4_t s[4];
#pragma unroll
    for (int nt = 0; nt < 4; ++nt) {
      s[nt] = (f4_t){0.f, 0.f, 0.f, 0.f};
      const int col = nt * 16 + lr;
#pragma unroll
      for (int ks = 0; ks < 2; ++ks) {
        int slt = (ks * 4 + lg) ^ (col & 7);
        h8_t kh = *(const h8_t*)&KP[0][col][slt][0];
        h8_t kl = *(const h8_t*)&KP[1][col][slt][0];
        s[nt] = prod3(qf[ks][0], qf[ks][1], kh, kl, s[nt]);
      }
    }

    // ---- online softmax (row = 4*lg+i; reduce over lr via shfl) ----
#pragma unroll
    for (int i = 0; i < 4; ++i) {
      float rm = -__builtin_huge_valf();
#pragma unroll
      for (int nt = 0; nt < 4; ++nt) {
        s[nt][i] *= 0.125f;
        rm = fmaxf(rm, s[nt][i]);
      }
      rm = fmaxf(rm, __shfl_xor(rm, 1));
      rm = fmaxf(rm, __shfl_xor(rm, 2));
      rm = fmaxf(rm, __shfl_xor(rm, 4));
      rm = fmaxf(rm, __shfl_xor(rm, 8));
      float mnew = fmaxf(mrun[i], rm);
      float alpha = __expf(mrun[i] - mnew);
      float rs = 0.0f;
#pragma unroll
      for (int nt = 0; nt < 4; ++nt) {
        float p = __expf(s[nt][i] - mnew);
        s[nt][i] = p;
        rs += p;
      }
      rs += __shfl_xor(rs, 1);
      rs += __shfl_xor(rs, 2);
      rs += __shfl_xor(rs, 4);
      rs += __shfl_xor(rs, 8);
      lrun[i] = lrun[i] * alpha + rs;
      mrun[i] = mnew;
#pragma unroll
      for (int nt = 0; nt < 4; ++nt) oacc[nt][i] *= alpha;
    }

    __syncthreads();  // all waves done reading K tile -> safe to overwrite

    // ---- P -> KP (wave-private rows 0..127, 2 planes, swizzled) ----
#pragma unroll
    for (int nt = 0; nt < 4; ++nt)
#pragma unroll
      for (int i = 0; i < 4; ++i) {
        int qrow = w * 16 + 4 * lg + i;
        int kv = nt * 16 + lr;
        int kp = kv >> 3, j = kv & 7;
        int slt = kp ^ (qrow & 7);
        u16 h2, l2;
        split2(s[nt][i], h2, l2);
        KP[0][qrow][slt][j] = h2;
        KP[1][qrow][slt][j] = l2;
      }

    // ---- O += P V (A = own P rows, B = Vt cols) ----
    h8_t pf[2][2];
#pragma unroll
    for (int ks = 0; ks < 2; ++ks) {
      int row = w * 16 + lr;
      int slt = (ks * 4 + lg) ^ (row & 7);
      pf[ks][0] = *(const h8_t*)&KP[0][row][slt][0];
      pf[ks][1] = *(const h8_t*)&KP[1][row][slt][0];
    }
#pragma unroll
    for (int ntd = 0; ntd < 4; ++ntd) {
      const int col = ntd * 16 + lr;
#pragma unroll
      for (int ks = 0; ks < 2; ++ks) {
        int slt = (ks * 4 + lg) ^ (col & 7);
        h8_t vh = *(const h8_t*)&Vs[0][col][slt][0];
        h8_t vl = *(const h8_t*)&Vs[1][col][slt][0];
        oacc[ntd] = prod3(pf[ks][0], pf[ks][1], vh, vl, oacc[ntd]);
      }
    }
  }

  // ---- epilogue: normalize, split2, store planes [B,T,512] ----
#pragma unroll
  for (int i = 0; i < 4; ++i) {
    float inv = 1.0f / lrun[i];
    int t = qt * 128 + w * 16 + 4 * lg + i;
#pragma unroll
    for (int ntd = 0; ntd < 4; ++ntd) {
      int d = hh * 64 + ntd * 16 + lr;
      size_t idx = ((size_t)(b * 1024 + t)) * 512 + d;
      u16 h2, l2;
      split2(oacc[ntd][i] * inv, h2, l2);
      Oh[idx] = h2;
      Ol[idx] = l2;
    }
  }
}

// ---------------- row kernels ----------------
DEV float wave_sum(float v) {
#pragma unroll
  for (int off = 1; off < 64; off <<= 1) v += __shfl_xor(v, off);
  return v;
}

DEV void store8_split2(u16* H, u16* L, size_t base, const float* t) {
  u16 vh[8], vl[8];
#pragma unroll
  for (int j = 0; j < 8; ++j) split2(t[j], vh[j], vl[j]);
  *(ushort4*)&H[base] = make_ushort4(vh[0], vh[1], vh[2], vh[3]);
  *(ushort4*)&H[base + 4] = make_ushort4(vh[4], vh[5], vh[6], vh[7]);
  *(ushort4*)&L[base] = make_ushort4(vl[0], vl[1], vl[2], vl[3]);
  *(ushort4*)&L[base + 4] = make_ushort4(vl[4], vl[5], vl[6], vl[7]);
}

__global__ __launch_bounds__(256) void ln_split2(const float* __restrict__ x,
                                                 const float* __restrict__ g,
                                                 const float* __restrict__ b,
                                                 u16* __restrict__ yh,
                                                 u16* __restrict__ yl) {
  const int row = blockIdx.x * 4 + (threadIdx.x >> 6);
  const int lane = threadIdx.x & 63;
  const float* xr = x + (size_t)row * DMODEL;
  float v[8];
  *(float4*)&v[0] = *(const float4*)(xr + lane * 8);
  *(float4*)&v[4] = *(const float4*)(xr + lane * 8 + 4);
  float s = 0.0f;
#pragma unroll
  for (int j = 0; j < 8; ++j) s += v[j];
  s = wave_sum(s);
  float mean = s * (1.0f / 512.0f);
  float s2 = 0.0f;
#pragma unroll
  for (int j = 0; j < 8; ++j) {
    float d = v[j] - mean;
    s2 += d * d;
  }
  s2 = wave_sum(s2);
  float rstd = 1.0f / sqrtf(s2 * (1.0f / 512.0f) + 1e-5f);
  float gg[8], bv[8];
  *(float4*)&gg[0] = *(const float4*)(g + lane * 8);
  *(float4*)&gg[4] = *(const float4*)(g + lane * 8 + 4);
  *(float4*)&bv[0] = *(const float4*)(b + lane * 8);
  *(float4*)&bv[4] = *(const float4*)(b + lane * 8 + 4);
  float t[8];
#pragma unroll
  for (int j = 0; j < 8; ++j) t[j] = (v[j] - mean) * rstd * gg[j] + bv[j];
  store8_split2(yh, yl, (size_t)row * DMODEL + lane * 8, t);
}

// LN + l2norm -> 2 fp16 planes (VQ head Q)
__global__ __launch_bounds__(256) void ln_l2_split2(
    const float* __restrict__ x, const float* __restrict__ g,
    const float* __restrict__ b, u16* __restrict__ yh, u16* __restrict__ yl) {
  const int row = blockIdx.x * 4 + (threadIdx.x >> 6);
  const int lane = threadIdx.x & 63;
  const float* xr = x + (size_t)row * DMODEL;
  float v[8];
  *(float4*)&v[0] = *(const float4*)(xr + lane * 8);
  *(float4*)&v[4] = *(const float4*)(xr + lane * 8 + 4);
  float s = 0.0f;
#pragma unroll
  for (int j = 0; j < 8; ++j) s += v[j];
  s = wave_sum(s);
  float mean = s * (1.0f / 512.0f);
  float s2 = 0.0f;
#pragma unroll
  for (int j = 0; j < 8; ++j) {
    float d = v[j] - mean;
    s2 += d * d;
  }
  s2 = wave_sum(s2);
  float rstd = 1.0f / sqrtf(s2 * (1.0f / 512.0f) + 1e-5f);
  float gg[8], bv[8];
  *(float4*)&gg[0] = *(const float4*)(g + lane * 8);
  *(float4*)&gg[4] = *(const float4*)(g + lane * 8 + 4);
  *(float4*)&bv[0] = *(const float4*)(b + lane * 8);
  *(float4*)&bv[4] = *(const float4*)(b + lane * 8 + 4);
  float t[8];
#pragma unroll
  for (int j = 0; j < 8; ++j) t[j] = (v[j] - mean) * rstd * gg[j] + bv[j];
  float n2 = 0.0f;
#pragma unroll
  for (int j = 0; j < 8; ++j) n2 += t[j] * t[j];
  n2 = wave_sum(n2);
  float den = fmaxf(sqrtf(n2), 1e-12f);
#pragma unroll
  for (int j = 0; j < 8; ++j) t[j] /= den;
  store8_split2(yh, yl, (size_t)row * DMODEL + lane * 8, t);
}

__global__ __launch_bounds__(256) void l2_split2(const float* __restrict__ x,
                                                 u16* __restrict__ yh,
                                                 u16* __restrict__ yl) {
  const int row = blockIdx.x * 4 + (threadIdx.x >> 6);
  const int lane = threadIdx.x & 63;
  const float* xr = x + (size_t)row * DMODEL;
  float v[8];
  *(float4*)&v[0] = *(const float4*)(xr + lane * 8);
  *(float4*)&v[4] = *(const float4*)(xr + lane * 8 + 4);
  float n2 = 0.0f;
#pragma unroll
  for (int j = 0; j < 8; ++j) n2 += v[j] * v[j];
  n2 = wave_sum(n2);
  float den = fmaxf(sqrtf(n2), 1e-12f);
#pragma unroll
  for (int j = 0; j < 8; ++j) v[j] /= den;
  store8_split2(yh, yl, (size_t)row * DMODEL + lane * 8, v);
}

// softmax over rows of 1024, in-place on 2 fp16 planes
__global__ __launch_bounds__(256) void softmax2(u16* __restrict__ H,
                                                u16* __restrict__ L) {
  const int row = blockIdx.x;
  const int tid = threadIdx.x;
  const size_t base = (size_t)row * 1024 + tid * 4;
  ushort4 qh = *(const ushort4*)&H[base];
  ushort4 ql = *(const ushort4*)&L[base];
  float v0 = h2f(qh.x) + h2f(ql.x);
  float v1 = h2f(qh.y) + h2f(ql.y);
  float v2 = h2f(qh.z) + h2f(ql.z);
  float v3 = h2f(qh.w) + h2f(ql.w);
  float mx = fmaxf(fmaxf(v0, v1), fmaxf(v2, v3));
#pragma unroll
  for (int off = 1; off < 64; off <<= 1) mx = fmaxf(mx, __shfl_xor(mx, off));
  __shared__ float red[4];
  const int wv = tid >> 6;
  if ((tid & 63) == 0) red[wv] = mx;
  __syncthreads();
  mx = fmaxf(fmaxf(red[0], red[1]), fmaxf(red[2], red[3]));
  float e0 = __expf(v0 - mx), e1 = __expf(v1 - mx), e2 = __expf(v2 - mx),
        e3 = __expf(v3 - mx);
  float s = e0 + e1 + e2 + e3;
#pragma unroll
  for (int off = 1; off < 64; off <<= 1) s += __shfl_xor(s, off);
  __syncthreads();
  if ((tid & 63) == 0) red[wv] = s;
  __syncthreads();
  s = red[0] + red[1] + red[2] + red[3];
  float inv = 1.0f / s;
  u16 ah[4], al[4];
  split2(e0 * inv, ah[0], al[0]);
  split2(e1 * inv, ah[1], al[1]);
  split2(e2 * inv, ah[2], al[2]);
  split2(e3 * inv, ah[3], al[3]);
  *(ushort4*)&H[base] = make_ushort4(ah[0], ah[1], ah[2], ah[3]);
  *(ushort4*)&L[base] = make_ushort4(al[0], al[1], al[2], al[3]);
}

// generic fp32 -> 2 fp16 planes splitter (n4 = n/4)
__global__ __launch_bounds__(256) void split2_k(const float* __restrict__ src,
                                                u16* __restrict__ H,
                                                u16* __restrict__ L, int n4) {
  for (int e = blockIdx.x * 256 + threadIdx.x; e < n4; e += gridDim.x * 256) {
    float4 v = *(const float4*)(src + (size_t)e * 4);
    u16 ah[4], al[4];
    split2(v.x, ah[0], al[0]);
    split2(v.y, ah[1], al[1]);
    split2(v.z, ah[2], al[2]);
    split2(v.w, ah[3], al[3]);
    *(ushort4*)&H[(size_t)e * 4] = make_ushort4(ah[0], ah[1], ah[2], ah[3]);
    *(ushort4*)&L[(size_t)e * 4] = make_ushort4(al[0], al[1], al[2], al[3]);
  }
}

// fused 4-region weight splitter: one launch replaces 4 split2_k (R25:
// launch-overhead reduction; work identical, grid-stride over each region)
__global__ __launch_bounds__(256) void split2_w4(
    const float* __restrict__ s0, u16* __restrict__ H0, u16* __restrict__ L0,
    int n0, const float* __restrict__ s1, u16* __restrict__ H1,
    u16* __restrict__ L1, int n1, const float* __restrict__ s2,
    u16* __restrict__ H2, u16* __restrict__ L2, int n2,
    const float* __restrict__ s3, u16* __restrict__ H3, u16* __restrict__ L3,
    int n3) {
  auto run = [&](const float* src, u16* H, u16* L, int n4) {
    for (int e = blockIdx.x * 256 + threadIdx.x; e < n4;
         e += gridDim.x * 256) {
      float4 v = *(const float4*)(src + (size_t)e * 4);
      u16 ah[4], al[4];
      split2(v.x, ah[0], al[0]);
      split2(v.y, ah[1], al[1]);
      split2(v.z, ah[2], al[2]);
      split2(v.w, ah[3], al[3]);
      *(ushort4*)&H[(size_t)e * 4] = make_ushort4(ah[0], ah[1], ah[2], ah[3]);
      *(ushort4*)&L[(size_t)e * 4] = make_ushort4(al[0], al[1], al[2], al[3]);
    }
  };
  run(s0, H0, L0, n0);
  run(s1, H1, L1, n1);
  run(s2, H2, L2, n2);
  run(s3, H3, L3, n3);
}

// transpose codebook [1024][512] -> cbT [512][1024], split into 2 planes
__global__ __launch_bounds__(256) void tsplit_cb(const float* __restrict__ cb,
                                                 u16* __restrict__ th,
                                                 u16* __restrict__ tl) {
  const int c = blockIdx.x;
  const int t = threadIdx.x;
  u16 ah[4], al[4];
#pragma unroll
  for (int j = 0; j < 4; ++j) {
    float v = cb[(size_t)(4 * t + j) * 512 + c];
    split2(v, ah[j], al[j]);
  }
  const size_t base = (size_t)c * 1024 + 4 * t;
  *(ushort4*)&th[base] = make_ushort4(ah[0], ah[1], ah[2], ah[3]);
  *(ushort4*)&tl[base] = make_ushort4(al[0], al[1], al[2], al[3]);
}

__global__ __launch_bounds__(256) void vq_finalize(
    const float* __restrict__ logits, const float* __restrict__ patterns,
    float* __restrict__ emb, float* __restrict__ assign,
    float* __restrict__ idxf) {
  const int row = blockIdx.x * 4 + (threadIdx.x >> 6);
  const int lane = threadIdx.x & 63;
  const float* lr = logits + (size_t)row * NPAT;
  float best = -__builtin_huge_valf();
  int bi = 0;
#pragma unroll
  for (int jj = 0; jj < 8; ++jj) {
    int j = lane + jj * 64;
    float v = lr[j];
    if (v > best) {
      best = v;
      bi = j;
    }
  }
#pragma unroll
  for (int off = 1; off < 64; off <<= 1) {
    float ob = __shfl_xor(best, off);
    int oi = __shfl_xor(bi, off);
    if (ob > best || (ob == best && oi < bi)) {
      best = ob;
      bi = oi;
    }
  }
  const float* pr = patterns + (size_t)bi * DMODEL;
#pragma unroll
  for (int g = 0; g < 2; ++g) {
    int c = lane * 8 + g * 4;
    float4 pv = *(const float4*)(pr + c);
    *(float4*)(emb + (size_t)row * DMODEL + c) = pv;
    float4 av;
    av.x = (c + 0 == bi) ? 1.0f : 0.0f;
    av.y = (c + 1 == bi) ? 1.0f : 0.0f;
    av.z = (c + 2 == bi) ? 1.0f : 0.0f;
    av.w = (c + 3 == bi) ? 1.0f : 0.0f;
    *(float4*)(assign + (size_t)row * NPAT + c) = av;
  }
  if (lane == 0) idxf[row] = (float)bi;
}

// ---------------- host launch ----------------
extern "C" void kernel_launch(void* const* d_in, const int* in_sizes, int n_in,
                              void* d_out, int out_size, void* d_ws,
                              size_t ws_size, hipStream_t stream) {
  (void)in_sizes;
  (void)n_in;
  (void)out_size;
  (void)ws_size;
  const float* x = (const float*)d_in[0];
  const float* gumbel = (const float*)d_in[1];
  const float* sym_w = (const float*)d_in[2];
  const float* sym_b = (const float*)d_in[3];
  const float* codebook = (const float*)d_in[4];
  const float* pos_enc = (const float*)d_in[5];
  const float* attn_in_w = (const float*)d_in[6];
  const float* attn_in_b = (const float*)d_in[7];
  const float* attn_out_w = (const float*)d_in[8];
  const float* attn_out_b = (const float*)d_in[9];
  const float* n1_g = (const float*)d_in[10];
  const float* n1_b = (const float*)d_in[11];
  const float* n2_g = (const float*)d_in[12];
  const float* n2_b = (const float*)d_in[13];
  const float* ffn_w1 = (const float*)d_in[14];
  const float* ffn_b1 = (const float*)d_in[15];
  const float* ffn_w2 = (const float*)d_in[16];
  const float* ffn_b2 = (const float*)d_in[17];
  const float* q_w = (const float*)d_in[18];
  const float* q_b = (const float*)d_in[19];
  const float* qln_g = (const float*)d_in[20];
  const float* qln_b = (const float*)d_in[21];
  const float* patterns = (const float*)d_in[22];
  const int* epoch = (const int*)d_in[23];
  const int* tot = (const int*)d_in[24];

  float* out = (float*)d_out;
  float* emb = out;               // [8192,512]
  float* assign = out + 4194304;  // [8192,512]
  float* logits = out + 8388608;  // [8192,512]
  float* h = out + 12582912;      // [8192,512]
  float* idxf = out + 16777216;   // [8192]

  float* ws_f = (float*)d_ws;
  // A region @0 (18.87M floats = 37.75M u16)
  u16* a16 = (u16*)ws_f;
  // B region @18.87M floats (6.29M floats = 12.58M u16)
  float* bF = ws_f + 18874368;
  u16* b16 = (u16*)bF;
  u16 *hnH = b16, *hnL = b16 + 4194304;
  // W region @25.17M floats (2.36M u16 capacity)
  float* wF = ws_f + 25165824;
  u16* w16 = (u16*)wF;

  // ---- symbolization ----
  u16 *xH = a16, *xL = a16 + 8388608;
  split2_k<<<2048, 256, 0, stream>>>(x, xH, xL, 2097152);
  split2_k<<<512, 256, 0, stream>>>(sym_w, w16, w16 + 524288, 131072);
  gemm_mf<64, E_BIAS><<<512, 256, 0, stream>>>(
      xH, xL, w16, w16 + 524288, sym_b, nullptr, bF, nullptr, nullptr, 512,
      1024, 1024, 1024, 4, nullptr, nullptr);
  l2_split2<<<256, 256, 0, stream>>>(codebook, w16, w16 + 524288);
  u16 *hpH = a16, *hpL = a16 + 4194304;
  l2_split2<<<2048, 256, 0, stream>>>(bF, hpH, hpL);
  u16 *sH = a16 + 12582912, *sL = a16 + 20971520;
  // gum: N=1024 -> 8-wave BN=256, grid 128*4=512
  gemm_mf8<E_GUM2><<<512, 512, 0, stream>>>(hpH, hpL, w16, w16 + 524288,
                                            nullptr, gumbel, nullptr, sH, sL,
                                            1024, 512, 512, 512, 4);
  softmax2<<<8192, 256, 0, stream>>>(sH, sL);
  tsplit_cb<<<512, 256, 0, stream>>>(codebook, w16, w16 + 524288);
  gemm_mf<64, E_POS><<<512, 256, 0, stream>>>(
      sH, sL, w16, w16 + 524288, nullptr, pos_enc, h, nullptr, nullptr, 512,
      1024, 1024, 1024, 4, nullptr, nullptr);

  // ---- transformer layers ----
  u16 *qkvH = a16, *qkvL = a16 + 12582912;
  u16* w1p = a16 + 33554432;            // 2 x 1048576 u16 (after qkv/mid)
  u16* w2p = b16 + 8388608;             // 2 x 1048576 u16 (after hn planes)
  u16 *pH = a16, *pL = a16 + 16777216;  // FFN mid [8192,2048] x2 planes
  // outw planes moved to disjoint W offsets so all 4 weight splits coexist:
  // inw [0,786432)+[786432,1572864); outw [1572864,1835008)+[1835008,2097152)
  u16* owH = w16 + 1572864;
  u16* owL = w16 + 1835008;

  for (int l = 0; l < 4; ++l) {
    const float* inw = attn_in_w + (size_t)l * 1536 * 512;
    const float* inb = attn_in_b + (size_t)l * 1536;
    const float* outw = attn_out_w + (size_t)l * 512 * 512;
    const float* outb = attn_out_b + (size_t)l * 512;
    const float* w1 = ffn_w1 + (size_t)l * 2048 * 512;
    const float* b1 = ffn_b1 + (size_t)l * 2048;
    const float* w2 = ffn_w2 + (size_t)l * 512 * 2048;
    const float* b2 = ffn_b2 + (size_t)l * 512;

    ln_split2<<<2048, 256, 0, stream>>>(h, n1_g + l * 512, n1_b + l * 512,
                                        hnH, hnL);
    // fused weight split: inw+outw+w1+w2 in ONE launch (was 4)
    split2_w4<<<2048, 256, 0, stream>>>(
        inw, w16, w16 + 786432, 196608, outw, owH, owL, 65536, w1, w1p,
        w1p + 1048576, 262144, w2, w2p, w2p + 1048576, 262144);
    // qkv: N=1536 -> 8-wave BN=256, grid 128*6=768
    gemm_mf8<E_QKV2><<<768, 512, 0, stream>>>(hnH, hnL, w16, w16 + 786432,
                                              inb, nullptr, nullptr, qkvH,
                                              qkvL, 1536, 512, 512, 512, 6);
    // flash: 8-wave, 128 q-rows/block, grid 512
    flash_mfma<<<512, 512, 0, stream>>>(qkvH, qkvL, hnH, hnL);
    gemm_mf<64, E_RES><<<512, 256, 0, stream>>>(
        hnH, hnL, owH, owL, outb, h, h, nullptr, nullptr, 512, 512, 512, 512,
        4, nullptr, nullptr);
    ln_split2<<<2048, 256, 0, stream>>>(h, n2_g + l * 512, n2_b + l * 512,
                                        hnH, hnL);
    // GELU: N=2048 -> 8-wave BN=256, grid 128*8=1024
    gemm_mf8<E_GELU2><<<1024, 512, 0, stream>>>(hnH, hnL, w1p, w1p + 1048576,
                                                b1, nullptr, nullptr, pH, pL,
                                                2048, 512, 512, 512, 8);
    // w2: single K=2048 GEMM with residual. Last layer: E_RES2 also emits the
    // split planes of h (into emb region as scratch; emb is written last by
    // vq_finalize) -> removes the VQ-head split2_k(h) + its 16MB re-read.
    if (l < 3) {
      gemm_mf<64, E_RES><<<512, 256, 0, stream>>>(
          pH, pL, w2p, w2p + 1048576, b2, h, h, nullptr, nullptr, 512, 2048,
          2048, 2048, 4, nullptr, nullptr);
    } else {
      gemm_mf<64, E_RES2><<<512, 256, 0, stream>>>(
          pH, pL, w2p, w2p + 1048576, b2, h, h, (u16*)out,
          (u16*)out + 4194304, 512, 2048, 2048, 2048, 4, nullptr, nullptr);
    }
  }

  // ---- VQ head (MFMA fp16 double-split) ----
  // h planes produced by last w2's E_RES2 into emb-region scratch
  u16* hsH = (u16*)out;
  u16* hsL = (u16*)out + 4194304;
  u16 *QpH = a16 + 8388608, *QpL = a16 + 12582912;  // Q planes
  split2_k<<<256, 256, 0, stream>>>(q_w, w16, w16 + 262144, 65536);
  gemm_mf<64, E_BIAS><<<512, 256, 0, stream>>>(
      hsH, hsL, w16, w16 + 262144, q_b, nullptr, bF, nullptr, nullptr, 512,
      512, 512, 512, 4, nullptr, nullptr);
  ln_l2_split2<<<2048, 256, 0, stream>>>(bF, qln_g, qln_b, QpH, QpL);
  l2_split2<<<128, 256, 0, stream>>>(patterns, w16 + 524288, w16 + 786432);
  gemm_mf<64, E_VQ><<<512, 256, 0, stream>>>(
      QpH, QpL, w16 + 524288, w16 + 786432, nullptr, nullptr, logits, nullptr,
      nullptr, 512, 512, 512, 512, 4, epoch, tot);
  vq_finalize<<<2048, 256, 0, stream>>>(logits, patterns, emb, assign, idxf);
}